// Round 1
// 1613.758 us; speedup vs baseline: 1.0838x; 1.0838x over previous
//
#include <hip/hip_runtime.h>
#include <math.h>

#define B_ 8
#define S_ 128
#define E_ 512
#define D_ 1024
#define H_ 16
#define L_ 4
#define V_ 32000
#define DH_ 64
#define FF_ 4096
#define M_ 1024      // S_*B_ rows, row = s*B_+b
#define ME_ 4096     // E_*B_ rows, row = e*B_+b
#define NT_ 250      // V_/128 vocab tiles
#define SCALE_F 0.125f
#define NEGV (-1e30f)

typedef __attribute__((ext_vector_type(8))) short short8;
typedef __attribute__((ext_vector_type(4))) float f32x4;

// ---------------- helpers ----------------
__device__ __forceinline__ float bf2f(ushort u) {
  union { unsigned int u32; float f; } v; v.u32 = ((unsigned int)u) << 16; return v.f;
}
__device__ __forceinline__ ushort f2bf(float x) {
  union { float f; unsigned int u; } v; v.f = x;
  unsigned int r = v.u + 0x7fff + ((v.u >> 16) & 1);
  return (ushort)(r >> 16);
}
__device__ __forceinline__ void gl_lds16(const ushort* g, ushort* l) {
  __builtin_amdgcn_global_load_lds((const __attribute__((address_space(1))) void*)g,
                                   (__attribute__((address_space(3))) void*)l, 16, 0, 0);
}

__device__ __forceinline__ float warp_reduce_sum(float v) {
#pragma unroll
  for (int o = 32; o > 0; o >>= 1) v += __shfl_down(v, o);
  return v;
}
__device__ __forceinline__ float warp_reduce_max(float v) {
#pragma unroll
  for (int o = 32; o > 0; o >>= 1) v = fmaxf(v, __shfl_down(v, o));
  return v;
}
__device__ __forceinline__ float block_reduce_sum(float v, float* sred) {
  v = warp_reduce_sum(v);
  __syncthreads();
  if ((threadIdx.x & 63) == 0) sred[threadIdx.x >> 6] = v;
  __syncthreads();
  float s = 0.0f;
  int nw = blockDim.x >> 6;
  for (int w = 0; w < nw; ++w) s += sred[w];
  return s;
}
__device__ __forceinline__ float block_reduce_max(float v, float* sred) {
  v = warp_reduce_max(v);
  __syncthreads();
  if ((threadIdx.x & 63) == 0) sred[threadIdx.x >> 6] = v;
  __syncthreads();
  float s = -3.4e38f;
  int nw = blockDim.x >> 6;
  for (int w = 0; w < nw; ++w) s = fmaxf(s, sred[w]);
  return s;
}

// ---------------- cast / setup ----------------
__global__ __launch_bounds__(256) void castf_kernel(const float* __restrict__ in,
                                                    ushort* __restrict__ out, int n4) {
  int t = blockIdx.x * 256 + threadIdx.x;
  if (t >= n4) return;
  float4 v = ((const float4*)in)[t];
  ushort4 o;
  o.x = f2bf(v.x); o.y = f2bf(v.y); o.z = f2bf(v.z); o.w = f2bf(v.w);
  ((ushort4*)out)[t] = o;
}

// merged per-layer weight cast: qkv(3D^2) | o(D^2) | q(D^2) | io(D^2) | f1(4D^2) | f2(4D^2)
// segment sizes in float4 units (compile-time): 786432 | 262144 | 262144 | 262144 | 1048576 | 1048576
__global__ __launch_bounds__(256) void castlayer_kernel(
    const float* __restrict__ sqkv, const float* __restrict__ so,
    const float* __restrict__ sq, const float* __restrict__ sio,
    const float* __restrict__ sf1, const float* __restrict__ sf2,
    ushort* __restrict__ dqkv, ushort* __restrict__ dov,
    ushort* __restrict__ dq, ushort* __restrict__ dio,
    ushort* __restrict__ df1, ushort* __restrict__ df2) {
  int t = blockIdx.x * 256 + threadIdx.x;   // float4 index into concatenated segments
  const float* src; ushort* dst; int idx;
  if (t < 786432)       { src = sqkv; dst = dqkv; idx = t; }
  else if (t < 1048576) { src = so;  dst = dov; idx = t - 786432; }
  else if (t < 1310720) { src = sq;  dst = dq;  idx = t - 1048576; }
  else if (t < 1572864) { src = sio; dst = dio; idx = t - 1310720; }
  else if (t < 2621440) { src = sf1; dst = df1; idx = t - 1572864; }
  else if (t < 3670016) { src = sf2; dst = df2; idx = t - 2621440; }
  else return;
  float4 v = ((const float4*)src)[idx];
  ushort4 o4;
  o4.x = f2bf(v.x); o4.y = f2bf(v.y); o4.z = f2bf(v.z); o4.w = f2bf(v.w);
  ((ushort4*)dst)[idx] = o4;
}

// encoder_rep [b,e,d] -> rows (e*B+b)
__global__ __launch_bounds__(256) void enct_kernel(const float* __restrict__ enc,
                                                   ushort* __restrict__ encT) {
  int t = blockIdx.x * 256 + threadIdx.x;
  if (t >= ME_ * D_) return;
  int d = t & (D_ - 1);
  int row = t >> 10;
  int e = row >> 3, b = row & 7;
  encT[t] = f2bf(enc[((size_t)b * E_ + e) * D_ + d]);
}

__global__ __launch_bounds__(256) void pos_emb_kernel(ushort* __restrict__ r) {
  int t = blockIdx.x * 256 + threadIdx.x;
  if (t >= S_ * D_) return;
  int i = t / D_, j = t % D_;
  float pos = (float)(S_ - 1 - i);
  int jj = (j < D_ / 2) ? j : (j - D_ / 2);
  float invf = powf(10000.0f, -(float)(2 * jj) / (float)D_);
  float a = pos * invf;
  r[t] = f2bf((j < D_ / 2) ? sinf(a) : cosf(a));
}

__global__ __launch_bounds__(256) void embed_kernel(const int* __restrict__ ids,
                                                    const float* __restrict__ emb,
                                                    float* __restrict__ core,
                                                    ushort* __restrict__ core_bf) {
  int t = blockIdx.x * 256 + threadIdx.x;
  if (t >= M_ * D_) return;
  int d = t & (D_ - 1);
  int row = t >> 10;
  int s = row >> 3, b = row & 7;
  float v = emb[(size_t)ids[b * S_ + s] * D_ + d];
  core[t] = v;
  core_bf[t] = f2bf(v);
}

// ---------------- bf16 MFMA GEMM, 128x128 tile, batched + split-K ----------------
// EPI: 0 f32, 1 bf16, 3 bf16+bias, 4 bf16+bias+gelu
template <int EPI>
__global__ __launch_bounds__(256) void gemm_w_kernel(
    const ushort* __restrict__ A, const ushort* __restrict__ Bm,
    const float* __restrict__ bias, void* __restrict__ Cv,
    int M, int N, int K, int ksplit,
    long long Arow, long long Abatch, long long Brow, long long Bbatch,
    long long Crow, long long Cbatch, long long Csplit) {
  __shared__ ushort lA[128 * 32];
  __shared__ ushort lB[128 * 32];
  int tid = threadIdx.x;
  int bz = blockIdx.z;
  int batch = bz / ksplit, split = bz % ksplit;
  int kLen = K / ksplit, kStart = split * kLen;
  const ushort* Ab = A + (size_t)batch * Abatch;
  const ushort* Bb = Bm + (size_t)batch * Bbatch;
  int bm = blockIdx.y * 128, bn = blockIdx.x * 128;
  int lane = tid & 63, wave = tid >> 6;
  int wrow = (wave >> 1) * 64, wcol = (wave & 1) * 64;
  int quad = lane >> 4, l16 = lane & 15;
  f32x4 acc[4][4];
#pragma unroll
  for (int i = 0; i < 4; ++i)
#pragma unroll
    for (int j = 0; j < 4; ++j) { acc[i][j][0] = 0.f; acc[i][j][1] = 0.f; acc[i][j][2] = 0.f; acc[i][j][3] = 0.f; }
  int r0 = tid >> 2, c0 = (tid & 3) * 8;
  int r1 = (tid + 256) >> 2;
  for (int k0 = kStart; k0 < kStart + kLen; k0 += 32) {
    __syncthreads();
    gl_lds16(Ab + (size_t)(bm + r0) * Arow + k0 + c0, &lA[(size_t)tid * 8]);
    gl_lds16(Ab + (size_t)(bm + r1) * Arow + k0 + c0, &lA[(size_t)(256 + tid) * 8]);
    gl_lds16(Bb + (size_t)(bn + r0) * Brow + k0 + c0, &lB[(size_t)tid * 8]);
    gl_lds16(Bb + (size_t)(bn + r1) * Brow + k0 + c0, &lB[(size_t)(256 + tid) * 8]);
    __syncthreads();
    short8 af[4], bfr[4];
#pragma unroll
    for (int mi = 0; mi < 4; ++mi)
      af[mi] = *(const short8*)&lA[(size_t)(wrow + mi * 16 + l16) * 32 + quad * 8];
#pragma unroll
    for (int ni = 0; ni < 4; ++ni)
      bfr[ni] = *(const short8*)&lB[(size_t)(wcol + ni * 16 + l16) * 32 + quad * 8];
#pragma unroll
    for (int mi = 0; mi < 4; ++mi)
#pragma unroll
      for (int ni = 0; ni < 4; ++ni)
        acc[mi][ni] = __builtin_amdgcn_mfma_f32_16x16x32_bf16(af[mi], bfr[ni], acc[mi][ni], 0, 0, 0);
  }
#pragma unroll
  for (int mi = 0; mi < 4; ++mi) {
    int row0 = bm + wrow + mi * 16 + quad * 4;
#pragma unroll
    for (int ni = 0; ni < 4; ++ni) {
      int col = bn + wcol + ni * 16 + l16;
      float bv = 0.f;
      if (EPI >= 3) bv = bias[col];
#pragma unroll
      for (int r = 0; r < 4; ++r) {
        float v = acc[mi][ni][r] + bv;
        if (EPI == 4) v = 0.5f * v * (1.0f + erff(v * 0.70710678118654752f));
        size_t ci = (size_t)split * Csplit + (size_t)batch * Cbatch + (size_t)(row0 + r) * Crow + col;
        if (EPI == 0) ((float*)Cv)[ci] = v;
        else ((ushort*)Cv)[ci] = f2bf(v);
      }
    }
  }
}

// ---------------- vocab GEMM with fused softmax-stats epilogue ----------------
// A = headout_bf (row stride 2048), B = w_emb. grid (M/128, V/128), x = row tiles (fast)
// XCD-bijective swizzle (m204, nwg=2000, q=250, r=0): give each XCD a contiguous
// vocab-panel chunk so co-resident blocks on one XCD share the same B panel in L2.
__global__ __launch_bounds__(256) void vocab_kernel(const ushort* __restrict__ A,
                                                    const ushort* __restrict__ Bm,
                                                    float* __restrict__ tmax,
                                                    float* __restrict__ tsum) {
  __shared__ ushort lA[128 * 32];
  __shared__ ushort lB[128 * 32];
  __shared__ float smax[2][128];
  __shared__ float ssum[2][128];
  int tid = threadIdx.x;
  int orig = blockIdx.x + gridDim.x * blockIdx.y;   // x fast, 2000 blocks
  int wg = (orig & 7) * 250 + (orig >> 3);          // bijective: xcd*q + orig/8
  int bm = (wg & 7) * 128;                          // row tile
  int bnT = wg >> 3;                                // vocab tile index
  int bn = bnT * 128;
  int lane = tid & 63, wave = tid >> 6;
  int wrow = (wave >> 1) * 64, half = wave & 1, wcol = half * 64;
  int quad = lane >> 4, l16 = lane & 15;
  f32x4 acc[4][4];
#pragma unroll
  for (int i = 0; i < 4; ++i)
#pragma unroll
    for (int j = 0; j < 4; ++j) { acc[i][j][0] = 0.f; acc[i][j][1] = 0.f; acc[i][j][2] = 0.f; acc[i][j][3] = 0.f; }
  int r0 = tid >> 2, c0 = (tid & 3) * 8;
  int r1 = (tid + 256) >> 2;
  for (int k0 = 0; k0 < D_; k0 += 32) {
    __syncthreads();
    gl_lds16(A + (size_t)(bm + r0) * 2048 + k0 + c0, &lA[(size_t)tid * 8]);
    gl_lds16(A + (size_t)(bm + r1) * 2048 + k0 + c0, &lA[(size_t)(256 + tid) * 8]);
    gl_lds16(Bm + (size_t)(bn + r0) * D_ + k0 + c0, &lB[(size_t)tid * 8]);
    gl_lds16(Bm + (size_t)(bn + r1) * D_ + k0 + c0, &lB[(size_t)(256 + tid) * 8]);
    __syncthreads();
    short8 af[4], bfr[4];
#pragma unroll
    for (int mi = 0; mi < 4; ++mi)
      af[mi] = *(const short8*)&lA[(size_t)(wrow + mi * 16 + l16) * 32 + quad * 8];
#pragma unroll
    for (int ni = 0; ni < 4; ++ni)
      bfr[ni] = *(const short8*)&lB[(size_t)(wcol + ni * 16 + l16) * 32 + quad * 8];
#pragma unroll
    for (int mi = 0; mi < 4; ++mi)
#pragma unroll
      for (int ni = 0; ni < 4; ++ni)
        acc[mi][ni] = __builtin_amdgcn_mfma_f32_16x16x32_bf16(af[mi], bfr[ni], acc[mi][ni], 0, 0, 0);
  }
  // per-row max over this wave's 64 cols
#pragma unroll
  for (int mi = 0; mi < 4; ++mi)
#pragma unroll
    for (int r = 0; r < 4; ++r) {
      float lm = -3.4e38f;
#pragma unroll
      for (int ni = 0; ni < 4; ++ni) lm = fmaxf(lm, acc[mi][ni][r]);
#pragma unroll
      for (int o = 1; o < 16; o <<= 1) lm = fmaxf(lm, __shfl_xor(lm, o));
      if (l16 == 0) smax[half][wrow + mi * 16 + quad * 4 + r] = lm;
    }
  __syncthreads();
#pragma unroll
  for (int mi = 0; mi < 4; ++mi)
#pragma unroll
    for (int r = 0; r < 4; ++r) {
      int row = wrow + mi * 16 + quad * 4 + r;
      float m = fmaxf(smax[0][row], smax[1][row]);
      float ls = 0.f;
#pragma unroll
      for (int ni = 0; ni < 4; ++ni) ls += __expf(acc[mi][ni][r] - m);
#pragma unroll
      for (int o = 1; o < 16; o <<= 1) ls += __shfl_xor(ls, o);
      if (l16 == 0) ssum[half][row] = ls;
    }
  __syncthreads();
  if (tid < 128) {
    float m = fmaxf(smax[0][tid], smax[1][tid]);
    float s = ssum[0][tid] + ssum[1][tid];
    tmax[(size_t)(bm + tid) * NT_ + bnT] = m;
    tsum[(size_t)(bm + tid) * NT_ + bnT] = s;
  }
}

__global__ __launch_bounds__(256) void vocab_combine_kernel(const float* __restrict__ tmax,
                                                            const float* __restrict__ tsum,
                                                            float* __restrict__ rmax,
                                                            float* __restrict__ rsum) {
  __shared__ float sred[4];
  int m = blockIdx.x;
  float mx = -3.4e38f;
  for (int t = threadIdx.x; t < NT_; t += 256) mx = fmaxf(mx, tmax[(size_t)m * NT_ + t]);
  mx = block_reduce_max(mx, sred);
  float s = 0.f;
  for (int t = threadIdx.x; t < NT_; t += 256)
    s += tsum[(size_t)m * NT_ + t] * expf(tmax[(size_t)m * NT_ + t] - mx);
  s = block_reduce_sum(s, sred);
  if (threadIdx.x == 0) { rmax[m] = mx; rsum[m] = s; }
}

__global__ __launch_bounds__(256) void tlogit_kernel(const ushort* __restrict__ headout,
                                                     const ushort* __restrict__ emb,
                                                     const int* __restrict__ tgt,
                                                     float* __restrict__ tl) {
  __shared__ float sred[4];
  int m = blockIdx.x;
  int s = m >> 3, b = m & 7;
  int t = tgt[b * S_ + s];
  const ushort* a = headout + (size_t)m * 2048;
  const ushort* w = emb + (size_t)t * D_;
  float acc = 0.f;
  for (int i = threadIdx.x; i < D_; i += 256) acc += bf2f(a[i]) * bf2f(w[i]);
  acc = block_reduce_sum(acc, sred);
  if (threadIdx.x == 0) tl[m] = acc;
}

// ---------------- fused self-attention, one block per (b,h) ----------------
__global__ __launch_bounds__(256) void attn1_fused_kernel(const ushort* __restrict__ heads,
                                                          const ushort* __restrict__ rkproj,
                                                          const float* __restrict__ rw,
                                                          const float* __restrict__ rr,
                                                          ushort* __restrict__ attnA) {
  __shared__ float score[128][129];   // 66 KB
  __shared__ ushort pP[128][136];     // 34.8 KB
  __shared__ ushort vT[64][136];      // 17.4 KB
  int bz = blockIdx.x;
  int b = bz >> 4, n = bz & 15;
  int tid = threadIdx.x, lane = tid & 63, wave = tid >> 6;
  int quad = lane >> 4, l16 = lane & 15;
  int wrow = wave * 32;

  // stage V transposed: vT[d][j]
  {
    int j = tid >> 1, dbase = (tid & 1) * 32;
    const ushort* src = heads + (size_t)(j * 8 + b) * 3072 + 2048 + n * 64 + dbase;
#pragma unroll
    for (int c8 = 0; c8 < 4; ++c8) {
      short8 v8 = *(const short8*)(src + c8 * 8);
#pragma unroll
      for (int cc = 0; cc < 8; ++cc) vT[dbase + c8 * 8 + cc][j] = (ushort)v8[cc];
    }
  }

  // Q fragments with biases
  short8 qrw[2][2], qrr[2][2];
#pragma unroll
  for (int mi = 0; mi < 2; ++mi) {
    int i = wrow + mi * 16 + l16;
    const ushort* qp = heads + (size_t)(i * 8 + b) * 3072 + n * 64;
#pragma unroll
    for (int kc = 0; kc < 2; ++kc) {
      int k0 = kc * 32 + quad * 8;
      short8 qv = *(const short8*)(qp + k0);
      short8 w, rv;
#pragma unroll
      for (int t = 0; t < 8; ++t) {
        float q = bf2f((ushort)qv[t]);
        w[t] = (short)f2bf(q + rw[n * 64 + k0 + t]);
        rv[t] = (short)f2bf(q + rr[n * 64 + k0 + t]);
      }
      qrw[mi][kc] = w; qrr[mi][kc] = rv;
    }
  }

  // pass 1: AC -> score LDS
  {
    f32x4 acc[2][8];
#pragma unroll
    for (int i = 0; i < 2; ++i)
#pragma unroll
      for (int j = 0; j < 8; ++j) { acc[i][j][0]=0.f; acc[i][j][1]=0.f; acc[i][j][2]=0.f; acc[i][j][3]=0.f; }
#pragma unroll
    for (int kc = 0; kc < 2; ++kc) {
      int k0 = kc * 32 + quad * 8;
      short8 kf[8];
#pragma unroll
      for (int ni = 0; ni < 8; ++ni) {
        int j = ni * 16 + l16;
        kf[ni] = *(const short8*)(heads + (size_t)(j * 8 + b) * 3072 + 1024 + n * 64 + k0);
      }
#pragma unroll
      for (int mi = 0; mi < 2; ++mi)
#pragma unroll
        for (int ni = 0; ni < 8; ++ni)
          acc[mi][ni] = __builtin_amdgcn_mfma_f32_16x16x32_bf16(qrw[mi][kc], kf[ni], acc[mi][ni], 0, 0, 0);
    }
#pragma unroll
    for (int mi = 0; mi < 2; ++mi)
#pragma unroll
      for (int ni = 0; ni < 8; ++ni)
#pragma unroll
        for (int r = 0; r < 4; ++r)
          score[wrow + mi * 16 + quad * 4 + r][ni * 16 + l16] = acc[mi][ni][r];
  }
  // pass 2: BD pre-shift, add into score with rel-shift mapping
  {
    f32x4 acc[2][8];
#pragma unroll
    for (int i = 0; i < 2; ++i)
#pragma unroll
      for (int j = 0; j < 8; ++j) { acc[i][j][0]=0.f; acc[i][j][1]=0.f; acc[i][j][2]=0.f; acc[i][j][3]=0.f; }
#pragma unroll
    for (int kc = 0; kc < 2; ++kc) {
      int k0 = kc * 32 + quad * 8;
      short8 rkf[8];
#pragma unroll
      for (int ni = 0; ni < 8; ++ni) {
        int jp = ni * 16 + l16;
        rkf[ni] = *(const short8*)(rkproj + (size_t)jp * 1024 + n * 64 + k0);
      }
#pragma unroll
      for (int mi = 0; mi < 2; ++mi)
#pragma unroll
        for (int ni = 0; ni < 8; ++ni)
          acc[mi][ni] = __builtin_amdgcn_mfma_f32_16x16x32_bf16(qrr[mi][kc], rkf[ni], acc[mi][ni], 0, 0, 0);
    }
#pragma unroll
    for (int mi = 0; mi < 2; ++mi)
#pragma unroll
      for (int r = 0; r < 4; ++r) {
        int i = wrow + mi * 16 + quad * 4 + r;
#pragma unroll
        for (int ni = 0; ni < 8; ++ni) {
          int jp = ni * 16 + l16;
          if (jp >= 127 - i) score[i][jp - 127 + i] += acc[mi][ni][r];
        }
      }
  }
  // softmax (rows owned by same wave): row = tid>>1, half cols each
  {
    int row = tid >> 1, halfc = (tid & 1) * 64;
    float mx = -3.4e38f;
    for (int c = halfc; c < halfc + 64; ++c) {
      float v = (c <= row) ? score[row][c] * SCALE_F : -3.4e38f;
      mx = fmaxf(mx, v);
    }
    mx = fmaxf(mx, __shfl_xor(mx, 1));
    float s = 0.f;
    for (int c = halfc; c < halfc + 64; ++c) {
      float e = (c <= row) ? __expf(score[row][c] * SCALE_F - mx) : 0.f;
      score[row][c] = e;
      s += e;
    }
    s += __shfl_xor(s, 1);
    float inv = 1.0f / s;
    for (int c = halfc; c < halfc + 64; ++c) pP[row][c] = f2bf(score[row][c] * inv);
  }
  __syncthreads();  // vT + pP ready for all
  // PV: O[i][d] = sum_j P[i][j] V[j][d]
  {
    f32x4 acc[2][4];
#pragma unroll
    for (int i = 0; i < 2; ++i)
#pragma unroll
      for (int j = 0; j < 4; ++j) { acc[i][j][0]=0.f; acc[i][j][1]=0.f; acc[i][j][2]=0.f; acc[i][j][3]=0.f; }
#pragma unroll
    for (int kc = 0; kc < 4; ++kc) {
      int k0 = kc * 32 + quad * 8;
      short8 pf[2], vf[4];
#pragma unroll
      for (int mi = 0; mi < 2; ++mi)
        pf[mi] = *(const short8*)&pP[wrow + mi * 16 + l16][k0];
#pragma unroll
      for (int ni = 0; ni < 4; ++ni)
        vf[ni] = *(const short8*)&vT[ni * 16 + l16][k0];
#pragma unroll
      for (int mi = 0; mi < 2; ++mi)
#pragma unroll
        for (int ni = 0; ni < 4; ++ni)
          acc[mi][ni] = __builtin_amdgcn_mfma_f32_16x16x32_bf16(pf[mi], vf[ni], acc[mi][ni], 0, 0, 0);
    }
#pragma unroll
    for (int mi = 0; mi < 2; ++mi)
#pragma unroll
      for (int r = 0; r < 4; ++r) {
        int i = wrow + mi * 16 + quad * 4 + r;
#pragma unroll
        for (int ni = 0; ni < 4; ++ni)
          attnA[(size_t)(i * 8 + b) * 1024 + n * 64 + ni * 16 + l16] = f2bf(acc[mi][ni][r]);
      }
  }
}

// ---------------- fused cross-attention (flash over 4 E-tiles), block per (b,h) --------
__global__ __launch_bounds__(256) void attn2_fused_kernel(const float* __restrict__ q0,
                                                          const float* __restrict__ q1,
                                                          const ushort* __restrict__ kvproj,
                                                          const float* __restrict__ mask,
                                                          ushort* __restrict__ attnA) {
  __shared__ ushort vT[64][136];
  __shared__ ushort pP[128][136];
  __shared__ float mtile[128];
  int bz = blockIdx.x;
  int b = bz >> 4, n = bz & 15;
  int tid = threadIdx.x, lane = tid & 63, wave = tid >> 6;
  int quad = lane >> 4, l16 = lane & 15;
  int wrow = wave * 32;
  // Q frags: q0+q1 (split-K halves), f32 -> bf16
  short8 qf[2][2];
#pragma unroll
  for (int mi = 0; mi < 2; ++mi) {
    int i = wrow + mi * 16 + l16;
    size_t base = (size_t)(i * 8 + b) * 1024 + n * 64;
#pragma unroll
    for (int kc = 0; kc < 2; ++kc) {
      int k0 = kc * 32 + quad * 8;
      short8 v;
#pragma unroll
      for (int t = 0; t < 8; ++t) v[t] = (short)f2bf(q0[base + k0 + t] + q1[base + k0 + t]);
      qf[mi][kc] = v;
    }
  }
  float m_run[2][4], l_run[2][4];
#pragma unroll
  for (int mi = 0; mi < 2; ++mi)
#pragma unroll
    for (int r = 0; r < 4; ++r) { m_run[mi][r] = -3.0e38f; l_run[mi][r] = 0.f; }
  f32x4 accO[2][4];
#pragma unroll
  for (int i = 0; i < 2; ++i)
#pragma unroll
    for (int j = 0; j < 4; ++j) { accO[i][j][0]=0.f; accO[i][j][1]=0.f; accO[i][j][2]=0.f; accO[i][j][3]=0.f; }

  for (int et = 0; et < 4; ++et) {
    __syncthreads();  // previous tile's PV done before restaging
    // stage V2 tile transposed + mask tile
    {
      int j = tid >> 1, dbase = (tid & 1) * 32;
      int e = et * 128 + j;
      const ushort* src = kvproj + (size_t)(e * 8 + b) * 2048 + 1024 + n * 64 + dbase;
#pragma unroll
      for (int c8 = 0; c8 < 4; ++c8) {
        short8 v8 = *(const short8*)(src + c8 * 8);
#pragma unroll
        for (int cc = 0; cc < 8; ++cc) vT[dbase + c8 * 8 + cc][j] = (ushort)v8[cc];
      }
      if (tid < 128) mtile[tid] = (1.0f - mask[b * E_ + et * 128 + tid]) * NEGV;
    }
    // S tile
    f32x4 accS[2][8];
#pragma unroll
    for (int i = 0; i < 2; ++i)
#pragma unroll
      for (int j = 0; j < 8; ++j) { accS[i][j][0]=0.f; accS[i][j][1]=0.f; accS[i][j][2]=0.f; accS[i][j][3]=0.f; }
#pragma unroll
    for (int kc = 0; kc < 2; ++kc) {
      int k0 = kc * 32 + quad * 8;
      short8 kf[8];
#pragma unroll
      for (int ni = 0; ni < 8; ++ni) {
        int e = et * 128 + ni * 16 + l16;
        kf[ni] = *(const short8*)(kvproj + (size_t)(e * 8 + b) * 2048 + n * 64 + k0);
      }
#pragma unroll
      for (int mi = 0; mi < 2; ++mi)
#pragma unroll
        for (int ni = 0; ni < 8; ++ni)
          accS[mi][ni] = __builtin_amdgcn_mfma_f32_16x16x32_bf16(qf[mi][kc], kf[ni], accS[mi][ni], 0, 0, 0);
    }
    __syncthreads();  // vT, mtile ready
    // online softmax per owned row
#pragma unroll
    for (int mi = 0; mi < 2; ++mi)
#pragma unroll
      for (int r = 0; r < 4; ++r) {
        float v[8];
        float vmax = -3.4e38f;
#pragma unroll
        for (int ni = 0; ni < 8; ++ni) {
          v[ni] = accS[mi][ni][r] * SCALE_F + mtile[ni * 16 + l16];
          vmax = fmaxf(vmax, v[ni]);
        }
#pragma unroll
        for (int o = 1; o < 16; o <<= 1) vmax = fmaxf(vmax, __shfl_xor(vmax, o));
        float mnew = fmaxf(m_run[mi][r], vmax);
        float alpha = __expf(m_run[mi][r] - mnew);
        float ls = 0.f;
        int row = wrow + mi * 16 + quad * 4 + r;
#pragma unroll
        for (int ni = 0; ni < 8; ++ni) {
          float p = __expf(v[ni] - mnew);
          ls += p;
          pP[row][ni * 16 + l16] = f2bf(p);
        }
#pragma unroll
        for (int o = 1; o < 16; o <<= 1) ls += __shfl_xor(ls, o);
        l_run[mi][r] = l_run[mi][r] * alpha + ls;
        m_run[mi][r] = mnew;
#pragma unroll
        for (int ni = 0; ni < 4; ++ni) accO[mi][ni][r] *= alpha;
      }
    // PV accumulate (pP rows own-wave, vT via sync above)
#pragma unroll
    for (int kc = 0; kc < 4; ++kc) {
      int k0 = kc * 32 + quad * 8;
      short8 pf[2], vf[4];
#pragma unroll
      for (int mi = 0; mi < 2; ++mi)
        pf[mi] = *(const short8*)&pP[wrow + mi * 16 + l16][k0];
#pragma unroll
      for (int ni = 0; ni < 4; ++ni)
        vf[ni] = *(const short8*)&vT[ni * 16 + l16][k0];
#pragma unroll
      for (int mi = 0; mi < 2; ++mi)
#pragma unroll
        for (int ni = 0; ni < 4; ++ni)
          accO[mi][ni] = __builtin_amdgcn_mfma_f32_16x16x32_bf16(pf[mi], vf[ni], accO[mi][ni], 0, 0, 0);
    }
  }
  // finalize
#pragma unroll
  for (int mi = 0; mi < 2; ++mi)
#pragma unroll
    for (int r = 0; r < 4; ++r) {
      int i = wrow + mi * 16 + quad * 4 + r;
      float inv = 1.0f / l_run[mi][r];
#pragma unroll
      for (int ni = 0; ni < 4; ++ni)
        attnA[(size_t)(i * 8 + b) * 1024 + n * 64 + ni * 16 + l16] = f2bf(accO[mi][ni][r] * inv);
    }
}

// ---------------- add + layernorm with split-sum + optional bias ----------------
__global__ __launch_bounds__(256) void addln_kernel(const float* __restrict__ a,
                                                    const float* __restrict__ c,
                                                    int nsplit, long long cstride,
                                                    const float* __restrict__ bias,
                                                    const float* __restrict__ g,
                                                    const float* __restrict__ bb,
                                                    float* __restrict__ out,
                                                    ushort* __restrict__ out_bf) {
  __shared__ float sred[4];
  int row = blockIdx.x;
  const float* pa = a + (size_t)row * D_;
  float vals[4];
  float s = 0.f;
#pragma unroll
  for (int it = 0; it < 4; ++it) {
    int idx = threadIdx.x + it * 256;
    float v = pa[idx];
    for (int sp = 0; sp < nsplit; ++sp) v += c[(size_t)sp * cstride + (size_t)row * D_ + idx];
    if (bias) v += bias[idx];
    vals[it] = v;
    s += v;
  }
  s = block_reduce_sum(s, sred);
  float mean = s * (1.0f / D_);
  float ss = 0.f;
#pragma unroll
  for (int it = 0; it < 4; ++it) {
    float dd = vals[it] - mean;
    ss += dd * dd;
  }
  ss = block_reduce_sum(ss, sred);
  float inv = rsqrtf(ss * (1.0f / D_) + 1e-5f);
#pragma unroll
  for (int it = 0; it < 4; ++it) {
    int idx = threadIdx.x + it * 256;
    float r = (vals[it] - mean) * inv * g[idx] + bb[idx];
    out[(size_t)row * D_ + idx] = r;
    out_bf[(size_t)row * D_ + idx] = f2bf(r);
  }
}

__global__ __launch_bounds__(256) void mode_kernel(const float* __restrict__ core,
                                                   const float* __restrict__ mode_w,
                                                   const float* __restrict__ mode_b,
                                                   float* __restrict__ mode_sig) {
  __shared__ float sred[4];
  int m = blockIdx.x;
  const float* a = core + (size_t)m * D_;
  float s = 0.f;
  for (int t = threadIdx.x; t < D_; t += 256) s += a[t] * mode_w[t];
  s = block_reduce_sum(s, sred);
  if (threadIdx.x == 0) mode_sig[m] = 1.0f / (1.0f + expf(-(s + mode_b[0])));
}

// ---------------- final: copy attention + loss ----------------
__global__ __launch_bounds__(256) void final_kernel(const float* __restrict__ lg,
                                                    const int* __restrict__ ids,
                                                    const float* __restrict__ mask,
                                                    const int* __restrict__ tgt,
                                                    const float* __restrict__ mode_sig,
                                                    const float* __restrict__ tlogit,
                                                    const float* __restrict__ rmax,
                                                    const float* __restrict__ rsum,
                                                    float* __restrict__ loss_acc) {
  __shared__ float sred[4];
  int s = blockIdx.x, b = blockIdx.y;
  int m = s * B_ + b;
  size_t base = (size_t)(b * S_ + s) * E_;
  const long long LGS = (long long)B_ * S_ * E_;
  int tg = tgt[b * S_ + s];
  float lv[2];
  float mx = -3.4e38f;
#pragma unroll
  for (int it = 0; it < 2; ++it) {
    int e = threadIdx.x + it * 256;
    float raw = 0.f;
#pragma unroll
    for (int sp = 0; sp < 4; ++sp) raw += lg[sp * LGS + base + e];
    raw += (1.0f - mask[b * E_ + e]) * NEGV;
    lv[it] = raw;
    mx = fmaxf(mx, raw);
  }
  mx = block_reduce_max(mx, sred);
  float ssum = 0.f, csum = 0.f;
#pragma unroll
  for (int it = 0; it < 2; ++it) {
    int e = threadIdx.x + it * 256;
    float ev = expf(lv[it] - mx);
    ssum += ev;
    if (ids[b * E_ + e] == tg) csum += ev;
  }
  ssum = block_reduce_sum(ssum, sred);
  csum = block_reduce_sum(csum, sred);
  if (threadIdx.x == 0) {
    float copy_p = csum / ssum;
    float pv = expf(tlogit[m] - rmax[m]) / rsum[m];
    float msig = mode_sig[m];
    float predict = pv * msig + (1.0f - msig) * copy_p;
    float valid = (tg != 0) ? 1.0f : 0.0f;
    atomicAdd(&loss_acc[0], -logf(predict + 1e-6f) * valid);
    atomicAdd(&loss_acc[1], valid);
  }
}

__global__ void writeout_kernel(const float* __restrict__ loss_acc, float* __restrict__ out) {
  if (threadIdx.x < B_) out[threadIdx.x] = loss_acc[0] / loss_acc[1];
}

// ---------------- host ----------------
static void gw(hipStream_t st, int epi, const ushort* A, const ushort* B, const float* bias,
               void* C, int M, int N, int K,
               long long Ar, long long Ab, long long Br, long long Bb,
               long long Cr, long long Cb, int nb, int ksplit, long long Csplit) {
  dim3 g(N / 128, M / 128, nb * ksplit);
  switch (epi) {
    case 0: gemm_w_kernel<0><<<g, 256, 0, st>>>(A, B, bias, C, M, N, K, ksplit, Ar, Ab, Br, Bb, Cr, Cb, Csplit); break;
    case 1: gemm_w_kernel<1><<<g, 256, 0, st>>>(A, B, bias, C, M, N, K, ksplit, Ar, Ab, Br, Bb, Cr, Cb, Csplit); break;
    case 3: gemm_w_kernel<3><<<g, 256, 0, st>>>(A, B, bias, C, M, N, K, ksplit, Ar, Ab, Br, Bb, Cr, Cb, Csplit); break;
    case 4: gemm_w_kernel<4><<<g, 256, 0, st>>>(A, B, bias, C, M, N, K, ksplit, Ar, Ab, Br, Bb, Cr, Cb, Csplit); break;
  }
}
static void castTo(hipStream_t st, const float* src, ushort* dst, size_t count) {
  int n4 = (int)(count / 4);
  castf_kernel<<<(n4 + 255) / 256, 256, 0, st>>>(src, dst, n4);
}

extern "C" void kernel_launch(void* const* d_in, const int* in_sizes, int n_in,
                              void* d_out, int out_size, void* d_ws, size_t ws_size,
                              hipStream_t stream) {
  const int* input_ids = (const int*)d_in[0];
  const float* encoder_rep = (const float*)d_in[1];
  const float* input_mask = (const float*)d_in[2];
  const int* decode_input = (const int*)d_in[3];
  const int* decode_target = (const int*)d_in[4];
  const float* word_emb = (const float*)d_in[5];
  const float* qkv_w = (const float*)d_in[6];
  const float* r_w = (const float*)d_in[7];
  const float* o_w = (const float*)d_in[8];
  const float* kv_w = (const float*)d_in[9];
  const float* q_w = (const float*)d_in[10];
  const float* io_w = (const float*)d_in[11];
  const float* rr_bias = (const float*)d_in[12];
  const float* rw_bias = (const float*)d_in[13];
  const float* ln1_g = (const float*)d_in[14];
  const float* ln1_b = (const float*)d_in[15];
  const float* ln2_g = (const float*)d_in[16];
  const float* ln2_b = (const float*)d_in[17];
  const float* ffn_w1 = (const float*)d_in[18];
  const float* ffn_b1 = (const float*)d_in[19];
  const float* ffn_w2 = (const float*)d_in[20];
  const float* ffn_b2 = (const float*)d_in[21];
  const float* ln3_g = (const float*)d_in[22];
  const float* ln3_b = (const float*)d_in[23];
  const float* out_w = (const float*)d_in[24];
  const float* out_b = (const float*)d_in[25];
  const float* copy_w = (const float*)d_in[26];
  const float* copy_b = (const float*)d_in[27];
  const float* mode_w = (const float*)d_in[28];
  const float* mode_b = (const float*)d_in[29];
  float* out = (float*)d_out;

  char* base = (char*)d_ws;
  size_t off = 0;
  auto alloc = [&](size_t bytes) -> void* {
    void* p = base + off;
    off = (off + bytes + 255) & ~(size_t)255;
    return p;
  };

  // per-layer weight buffers (cast each layer, merged into one dispatch)
  ushort* wl_qkv = (ushort*)alloc((size_t)3 * D_ * D_ * 2);
  ushort* wl_o = (ushort*)alloc((size_t)D_ * D_ * 2);
  ushort* wl_q = (ushort*)alloc((size_t)D_ * D_ * 2);
  ushort* wl_io = (ushort*)alloc((size_t)D_ * D_ * 2);
  ushort* wl_f1 = (ushort*)alloc((size_t)FF_ * D_ * 2);
  ushort* wl_f2 = (ushort*)alloc((size_t)FF_ * D_ * 2);
  // hoisted all-layer buffers (encoder-side work batched upfront)
  ushort* wl_kv = (ushort*)alloc((size_t)L_ * 2 * D_ * D_ * 2);
  ushort* wl_r = (ushort*)alloc((size_t)L_ * D_ * D_ * 2);
  ushort* kvproj_bf = (ushort*)alloc((size_t)L_ * ME_ * 2 * D_ * 2);
  ushort* rkproj_bf = (ushort*)alloc((size_t)L_ * S_ * D_ * 2);

  ushort* w_emb = (ushort*)alloc((size_t)V_ * D_ * 2);
  ushort* w_oc = (ushort*)alloc((size_t)2048 * D_ * 2);
  float* b_oc = (float*)alloc(2048 * 4);
  ushort* enc_bf = (ushort*)alloc((size_t)ME_ * D_ * 2);
  ushort* encT_bf = (ushort*)alloc((size_t)ME_ * D_ * 2);
  ushort* r_bf = (ushort*)alloc((size_t)S_ * D_ * 2);
  float* f_core = (float*)alloc((size_t)M_ * D_ * 4);
  ushort* core_bf = (ushort*)alloc((size_t)M_ * D_ * 2);
  ushort* heads_bf = (ushort*)alloc((size_t)M_ * 3 * D_ * 2);
  ushort* attnA_bf = (ushort*)alloc((size_t)M_ * D_ * 2);
  float* f_tmp = (float*)alloc((size_t)4 * M_ * D_ * 4);   // up to 4 split buffers
  float* f_x = (float*)alloc((size_t)M_ * D_ * 4);
  ushort* x_bf = (ushort*)alloc((size_t)M_ * D_ * 2);
  float* f_y = (float*)alloc((size_t)M_ * D_ * 4);
  ushort* y_bf = (ushort*)alloc((size_t)M_ * D_ * 2);
  float* f_q = (float*)alloc((size_t)2 * M_ * D_ * 4);      // q split buffers
  ushort* ffnh_bf = (ushort*)alloc((size_t)M_ * FF_ * 2);
  ushort* headout_bf = (ushort*)alloc((size_t)M_ * 2048 * 2);
  float* f_lg = (float*)alloc((size_t)4 * B_ * S_ * E_ * 4);
  float* f_tmax = (float*)alloc((size_t)M_ * NT_ * 4);
  float* f_tsum = (float*)alloc((size_t)M_ * NT_ * 4);
  float* f_rmax = (float*)alloc(M_ * 4);
  float* f_rsum = (float*)alloc(M_ * 4);
  float* f_tlogit = (float*)alloc(M_ * 4);
  float* f_mode = (float*)alloc(M_ * 4);
  float* f_loss = (float*)alloc(64);

  // global casts + setup
  castTo(stream, word_emb, w_emb, (size_t)V_ * D_);
  castTo(stream, out_w, w_oc, (size_t)D_ * D_);
  castTo(stream, copy_w, w_oc + (size_t)D_ * D_, (size_t)D_ * D_);
  hipMemcpyAsync(b_oc, out_b, D_ * 4, hipMemcpyDeviceToDevice, stream);
  hipMemcpyAsync(b_oc + D_, copy_b, D_ * 4, hipMemcpyDeviceToDevice, stream);
  castTo(stream, encoder_rep, enc_bf, (size_t)ME_ * D_);
  enct_kernel<<<(ME_ * D_) / 256, 256, 0, stream>>>(encoder_rep, encT_bf);
  pos_emb_kernel<<<(S_ * D_ + 255) / 256, 256, 0, stream>>>(r_bf);
  embed_kernel<<<(M_ * D_) / 256, 256, 0, stream>>>(decode_input, word_emb, f_core, core_bf);

  // hoisted: all-layer kv/r weight casts + batched encoder-side projections
  castTo(stream, kv_w, wl_kv, (size_t)L_ * 2 * D_ * D_);
  castTo(stream, r_w, wl_r, (size_t)L_ * D_ * D_);
  // kvproj[l] = encT @ kv_w[l]^T : batched over layers (2048 blocks)
  gw(stream, 1, encT_bf, wl_kv, nullptr, kvproj_bf, ME_, 2 * D_, D_,
     D_, 0, D_, (long long)2 * D_ * D_, 2 * D_, (long long)ME_ * 2 * D_, L_, 1, 0);
  // rkproj[l] = r @ r_w[l]^T : batched over layers (32 blocks)
  gw(stream, 1, r_bf, wl_r, nullptr, rkproj_bf, S_, D_, D_,
     D_, 0, D_, (long long)D_ * D_, D_, (long long)S_ * D_, L_, 1, 0);

  for (int l = 0; l < L_; ++l) {
    // one merged cast for this layer's decoder-side weights
    castlayer_kernel<<<14336, 256, 0, stream>>>(
        qkv_w + (size_t)l * 3 * D_ * D_, o_w + (size_t)l * D_ * D_,
        q_w + (size_t)l * D_ * D_, io_w + (size_t)l * D_ * D_,
        ffn_w1 + (size_t)l * FF_ * D_, ffn_w2 + (size_t)l * FF_ * D_,
        wl_qkv, wl_o, wl_q, wl_io, wl_f1, wl_f2);

    // self-attention
    gw(stream, 1, core_bf, wl_qkv, nullptr, heads_bf, M_, 3 * D_, D_, D_, 0, D_, 0, 3 * D_, 0, 1, 1, 0);
    attn1_fused_kernel<<<B_ * H_, 256, 0, stream>>>(heads_bf, rkproj_bf + (size_t)l * S_ * D_,
                                                    rw_bias + (size_t)l * D_,
                                                    rr_bias + (size_t)l * D_, attnA_bf);
    gw(stream, 0, attnA_bf, wl_o, nullptr, f_tmp, M_, D_, D_, D_, 0, D_, 0, D_, 0, 1, 2,
       (long long)M_ * D_);
    addln_kernel<<<M_, 256, 0, stream>>>(f_core, f_tmp, 2, (long long)M_ * D_, nullptr,
                                         ln1_g + (size_t)l * D_, ln1_b + (size_t)l * D_, f_x, x_bf);

    // cross-attention (kvproj precomputed upfront)
    gw(stream, 0, x_bf, wl_q, nullptr, f_q, M_, D_, D_, D_, 0, D_, 0, D_, 0, 1, 2,
       (long long)M_ * D_);
    attn2_fused_kernel<<<B_ * H_, 256, 0, stream>>>(f_q, f_q + (size_t)M_ * D_,
                                                    kvproj_bf + (size_t)l * ME_ * 2 * D_,
                                                    input_mask, attnA_bf);
    gw(stream, 0, attnA_bf, wl_io, nullptr, f_tmp, M_, D_, D_, D_, 0, D_, 0, D_, 0, 1, 2,
       (long long)M_ * D_);
    addln_kernel<<<M_, 256, 0, stream>>>(f_x, f_tmp, 2, (long long)M_ * D_, nullptr,
                                         ln2_g + (size_t)l * D_, ln2_b + (size_t)l * D_, f_y, y_bf);

    // FFN
    gw(stream, 4, y_bf, wl_f1, ffn_b1 + (size_t)l * FF_, ffnh_bf, M_, FF_, D_, D_, 0, D_, 0, FF_, 0, 1, 1, 0);
    gw(stream, 0, ffnh_bf, wl_f2, nullptr, f_tmp, M_, D_, FF_, FF_, 0, FF_, 0, D_, 0, 1, 4,
       (long long)M_ * D_);
    addln_kernel<<<M_, 256, 0, stream>>>(f_y, f_tmp, 4, (long long)M_ * D_,
                                         ffn_b2 + (size_t)l * D_,
                                         ln3_g + (size_t)l * D_, ln3_b + (size_t)l * D_, f_core, core_bf);
  }

  // merged output+copy head GEMM: [M,2048]
  gw(stream, 3, core_bf, w_oc, b_oc, headout_bf, M_, 2048, D_, D_, 0, D_, 0, 2048, 0, 1, 1, 0);
  mode_kernel<<<M_, 256, 0, stream>>>(f_core, mode_w, mode_b, f_mode);

  // vocab softmax stats (XCD-swizzled for B-panel L2 locality)
  vocab_kernel<<<dim3(M_ / 128, V_ / 128), 256, 0, stream>>>(headout_bf, w_emb, f_tmax, f_tsum);
  vocab_combine_kernel<<<M_, 256, 0, stream>>>(f_tmax, f_tsum, f_rmax, f_rsum);
  tlogit_kernel<<<M_, 256, 0, stream>>>(headout_bf, w_emb, decode_target, f_tlogit);

  // copy logits: batched over b, split-K 4
  gw(stream, 0, headout_bf + D_, enc_bf, nullptr, f_lg, S_, E_, D_,
     (long long)B_ * 2048, 2048, D_, (long long)E_ * D_, E_, (long long)S_ * E_, B_, 4,
     (long long)B_ * S_ * E_);

  hipMemsetAsync(f_loss, 0, 2 * sizeof(float), stream);
  final_kernel<<<dim3(S_, B_), 256, 0, stream>>>(f_lg, input_ids, input_mask, decode_target,
                                                 f_mode, f_tlogit, f_rmax, f_rsum, f_loss);
  writeout_kernel<<<1, 64, 0, stream>>>(f_loss, out);
}

// Round 2
// 1588.151 us; speedup vs baseline: 1.1012x; 1.0161x over previous
//
#include <hip/hip_runtime.h>
#include <math.h>

#define B_ 8
#define S_ 128
#define E_ 512
#define D_ 1024
#define H_ 16
#define L_ 4
#define V_ 32000
#define DH_ 64
#define FF_ 4096
#define M_ 1024      // S_*B_ rows, row = s*B_+b
#define ME_ 4096     // E_*B_ rows, row = e*B_+b
#define NT_ 125      // V_/256 vocab tiles
#define SCALE_F 0.125f
#define NEGV (-1e30f)

typedef __attribute__((ext_vector_type(8))) short short8;
typedef __attribute__((ext_vector_type(4))) float f32x4;

// ---------------- helpers ----------------
__device__ __forceinline__ float bf2f(ushort u) {
  union { unsigned int u32; float f; } v; v.u32 = ((unsigned int)u) << 16; return v.f;
}
__device__ __forceinline__ ushort f2bf(float x) {
  union { float f; unsigned int u; } v; v.f = x;
  unsigned int r = v.u + 0x7fff + ((v.u >> 16) & 1);
  return (ushort)(r >> 16);
}
__device__ __forceinline__ void gl_lds16(const ushort* g, ushort* l) {
  __builtin_amdgcn_global_load_lds((const __attribute__((address_space(1))) void*)g,
                                   (__attribute__((address_space(3))) void*)l, 16, 0, 0);
}

__device__ __forceinline__ float warp_reduce_sum(float v) {
#pragma unroll
  for (int o = 32; o > 0; o >>= 1) v += __shfl_down(v, o);
  return v;
}
__device__ __forceinline__ float warp_reduce_max(float v) {
#pragma unroll
  for (int o = 32; o > 0; o >>= 1) v = fmaxf(v, __shfl_down(v, o));
  return v;
}
__device__ __forceinline__ float block_reduce_sum(float v, float* sred) {
  v = warp_reduce_sum(v);
  __syncthreads();
  if ((threadIdx.x & 63) == 0) sred[threadIdx.x >> 6] = v;
  __syncthreads();
  float s = 0.0f;
  int nw = blockDim.x >> 6;
  for (int w = 0; w < nw; ++w) s += sred[w];
  return s;
}
__device__ __forceinline__ float block_reduce_max(float v, float* sred) {
  v = warp_reduce_max(v);
  __syncthreads();
  if ((threadIdx.x & 63) == 0) sred[threadIdx.x >> 6] = v;
  __syncthreads();
  float s = -3.4e38f;
  int nw = blockDim.x >> 6;
  for (int w = 0; w < nw; ++w) s = fmaxf(s, sred[w]);
  return s;
}

// ---------------- cast / setup ----------------
__global__ __launch_bounds__(256) void castf_kernel(const float* __restrict__ in,
                                                    ushort* __restrict__ out, int n4) {
  int t = blockIdx.x * 256 + threadIdx.x;
  if (t >= n4) return;
  float4 v = ((const float4*)in)[t];
  ushort4 o;
  o.x = f2bf(v.x); o.y = f2bf(v.y); o.z = f2bf(v.z); o.w = f2bf(v.w);
  ((ushort4*)out)[t] = o;
}

// merged per-layer weight cast: qkv(3D^2) | o(D^2) | q(D^2) | io(D^2) | f1(4D^2) | f2(4D^2)
__global__ __launch_bounds__(256) void castlayer_kernel(
    const float* __restrict__ sqkv, const float* __restrict__ so,
    const float* __restrict__ sq, const float* __restrict__ sio,
    const float* __restrict__ sf1, const float* __restrict__ sf2,
    ushort* __restrict__ dqkv, ushort* __restrict__ dov,
    ushort* __restrict__ dq, ushort* __restrict__ dio,
    ushort* __restrict__ df1, ushort* __restrict__ df2) {
  int t = blockIdx.x * 256 + threadIdx.x;   // float4 index into concatenated segments
  const float* src; ushort* dst; int idx;
  if (t < 786432)       { src = sqkv; dst = dqkv; idx = t; }
  else if (t < 1048576) { src = so;  dst = dov; idx = t - 786432; }
  else if (t < 1310720) { src = sq;  dst = dq;  idx = t - 1048576; }
  else if (t < 1572864) { src = sio; dst = dio; idx = t - 1310720; }
  else if (t < 2621440) { src = sf1; dst = df1; idx = t - 1572864; }
  else if (t < 3670016) { src = sf2; dst = df2; idx = t - 2621440; }
  else return;
  float4 v = ((const float4*)src)[idx];
  ushort4 o4;
  o4.x = f2bf(v.x); o4.y = f2bf(v.y); o4.z = f2bf(v.z); o4.w = f2bf(v.w);
  ((ushort4*)dst)[idx] = o4;
}

// encoder_rep [b,e,d] -> rows (e*B+b)
__global__ __launch_bounds__(256) void enct_kernel(const float* __restrict__ enc,
                                                   ushort* __restrict__ encT) {
  int t = blockIdx.x * 256 + threadIdx.x;
  if (t >= ME_ * D_) return;
  int d = t & (D_ - 1);
  int row = t >> 10;
  int e = row >> 3, b = row & 7;
  encT[t] = f2bf(enc[((size_t)b * E_ + e) * D_ + d]);
}

__global__ __launch_bounds__(256) void pos_emb_kernel(ushort* __restrict__ r) {
  int t = blockIdx.x * 256 + threadIdx.x;
  if (t >= S_ * D_) return;
  int i = t / D_, j = t % D_;
  float pos = (float)(S_ - 1 - i);
  int jj = (j < D_ / 2) ? j : (j - D_ / 2);
  float invf = powf(10000.0f, -(float)(2 * jj) / (float)D_);
  float a = pos * invf;
  r[t] = f2bf((j < D_ / 2) ? sinf(a) : cosf(a));
}

__global__ __launch_bounds__(256) void embed_kernel(const int* __restrict__ ids,
                                                    const float* __restrict__ emb,
                                                    float* __restrict__ core,
                                                    ushort* __restrict__ core_bf) {
  int t = blockIdx.x * 256 + threadIdx.x;
  if (t >= M_ * D_) return;
  int d = t & (D_ - 1);
  int row = t >> 10;
  int s = row >> 3, b = row & 7;
  float v = emb[(size_t)ids[b * S_ + s] * D_ + d];
  core[t] = v;
  core_bf[t] = f2bf(v);
}

// ---------------- bf16 MFMA GEMM, 128x128 tile, batched + split-K ----------------
// EPI: 0 f32, 1 bf16, 3 bf16+bias, 4 bf16+bias+gelu
template <int EPI>
__global__ __launch_bounds__(256) void gemm_w_kernel(
    const ushort* __restrict__ A, const ushort* __restrict__ Bm,
    const float* __restrict__ bias, void* __restrict__ Cv,
    int M, int N, int K, int ksplit,
    long long Arow, long long Abatch, long long Brow, long long Bbatch,
    long long Crow, long long Cbatch, long long Csplit) {
  __shared__ ushort lA[128 * 32];
  __shared__ ushort lB[128 * 32];
  int tid = threadIdx.x;
  int bz = blockIdx.z;
  int batch = bz / ksplit, split = bz % ksplit;
  int kLen = K / ksplit, kStart = split * kLen;
  const ushort* Ab = A + (size_t)batch * Abatch;
  const ushort* Bb = Bm + (size_t)batch * Bbatch;
  int bm = blockIdx.y * 128, bn = blockIdx.x * 128;
  int lane = tid & 63, wave = tid >> 6;
  int wrow = (wave >> 1) * 64, wcol = (wave & 1) * 64;
  int quad = lane >> 4, l16 = lane & 15;
  f32x4 acc[4][4];
#pragma unroll
  for (int i = 0; i < 4; ++i)
#pragma unroll
    for (int j = 0; j < 4; ++j) { acc[i][j][0] = 0.f; acc[i][j][1] = 0.f; acc[i][j][2] = 0.f; acc[i][j][3] = 0.f; }
  int r0 = tid >> 2, c0 = (tid & 3) * 8;
  int r1 = (tid + 256) >> 2;
  for (int k0 = kStart; k0 < kStart + kLen; k0 += 32) {
    __syncthreads();
    gl_lds16(Ab + (size_t)(bm + r0) * Arow + k0 + c0, &lA[(size_t)tid * 8]);
    gl_lds16(Ab + (size_t)(bm + r1) * Arow + k0 + c0, &lA[(size_t)(256 + tid) * 8]);
    gl_lds16(Bb + (size_t)(bn + r0) * Brow + k0 + c0, &lB[(size_t)tid * 8]);
    gl_lds16(Bb + (size_t)(bn + r1) * Brow + k0 + c0, &lB[(size_t)(256 + tid) * 8]);
    __syncthreads();
    short8 af[4], bfr[4];
#pragma unroll
    for (int mi = 0; mi < 4; ++mi)
      af[mi] = *(const short8*)&lA[(size_t)(wrow + mi * 16 + l16) * 32 + quad * 8];
#pragma unroll
    for (int ni = 0; ni < 4; ++ni)
      bfr[ni] = *(const short8*)&lB[(size_t)(wcol + ni * 16 + l16) * 32 + quad * 8];
#pragma unroll
    for (int mi = 0; mi < 4; ++mi)
#pragma unroll
      for (int ni = 0; ni < 4; ++ni)
        acc[mi][ni] = __builtin_amdgcn_mfma_f32_16x16x32_bf16(af[mi], bfr[ni], acc[mi][ni], 0, 0, 0);
  }
#pragma unroll
  for (int mi = 0; mi < 4; ++mi) {
    int row0 = bm + wrow + mi * 16 + quad * 4;
#pragma unroll
    for (int ni = 0; ni < 4; ++ni) {
      int col = bn + wcol + ni * 16 + l16;
      float bv = 0.f;
      if (EPI >= 3) bv = bias[col];
#pragma unroll
      for (int r = 0; r < 4; ++r) {
        float v = acc[mi][ni][r] + bv;
        if (EPI == 4) v = 0.5f * v * (1.0f + erff(v * 0.70710678118654752f));
        size_t ci = (size_t)split * Csplit + (size_t)batch * Cbatch + (size_t)(row0 + r) * Crow + col;
        if (EPI == 0) ((float*)Cv)[ci] = v;
        else ((ushort*)Cv)[ci] = f2bf(v);
      }
    }
  }
}

// ---------------- 256x256-tile deep-pipelined GEMM (BK=32, 4-deep LDS ring) ----------
// T3+T4: counted vmcnt (never 0 in steady state) keeps 2 K-tiles of staging in flight
// across raw s_barrier; T5: setprio around MFMA clusters.
// EPI 1: bf16 C store (kvproj, batched over layers, grid x=N/256, y=M/256, z=batch)
// EPI 5: vocab softmax-stats epilogue (1-D grid, XCD-bijective swizzle, M=1024 N=32000)
template <int EPI>
__global__ __launch_bounds__(512, 2) void gemm256_kernel(
    const ushort* __restrict__ A, const ushort* __restrict__ Bm, void* __restrict__ Cv,
    float* __restrict__ tmax, float* __restrict__ tsum,
    long long Arow, long long Abatch, long long Brow, long long Bbatch,
    long long Crow, long long Cbatch) {
  // [buf][A=0/B=1][half][128 rows x 32 cols] : 4 x 32KB = 128 KB
  __shared__ ushort sT[4][2][2][128 * 32];
  __shared__ float smax[256][4];
  __shared__ float ssum[256][4];
  const int NK = 32;  // K = 1024 = 32 K-tiles of BK=32
  int tid = threadIdx.x;
  int bm, bn, bnT = 0, batch = 0;
  if constexpr (EPI == 5) {
    // bijective m204 swizzle, nwg=500: q=62, r=4 (xcd<4 gets 63 blocks)
    int orig = blockIdx.x;
    int xcd = orig & 7;
    int base = (xcd < 4) ? xcd * 63 : 4 * 63 + (xcd - 4) * 62;
    int wg = base + (orig >> 3);
    bm = (wg & 3) * 256;          // row tile fast -> co-resident blocks share B panel
    bnT = wg >> 2;
    bn = bnT * 256;
  } else {
    bn = blockIdx.x * 256;
    bm = blockIdx.y * 256;
    batch = blockIdx.z;
  }
  const ushort* Ab = A + (size_t)batch * Abatch;
  const ushort* Bb = Bm + (size_t)batch * Bbatch;
  int lane = tid & 63, wave = tid >> 6;
  int wr = wave >> 2;          // 0..1 : row half (128 rows)
  int wc = wave & 3;           // 0..3 : col quarter (64 cols)
  int bhalf = wc >> 1;         // B half this wave reads
  int brow0 = (wc & 1) * 64;   // row base within B half
  int quad = lane >> 4, l16 = lane & 15;
  // staging coords
  int sr = tid >> 2, sc = (tid & 3) * 8;

  f32x4 acc[8][4];
#pragma unroll
  for (int i = 0; i < 8; ++i)
#pragma unroll
    for (int j = 0; j < 4; ++j) { acc[i][j][0]=0.f; acc[i][j][1]=0.f; acc[i][j][2]=0.f; acc[i][j][3]=0.f; }

  // stage one half-tile (1 gl_lds per thread): ab=0 A, ab=1 B; h = row-half
#define STAGE_HALF(s_, ab_, h_)                                                        \
  do {                                                                                 \
    int s__ = (s_); int b__ = s__ & 3;                                                 \
    if ((ab_) == 0)                                                                    \
      gl_lds16(Ab + (size_t)(bm + (h_) * 128 + sr) * Arow + s__ * 32 + sc,             \
               &sT[b__][0][h_][tid * 8]);                                              \
    else                                                                               \
      gl_lds16(Bb + (size_t)(bn + (h_) * 128 + sr) * Brow + s__ * 32 + sc,             \
               &sT[b__][1][h_][tid * 8]);                                              \
  } while (0)

  // prologue: stage tiles 0,1,2 (12 loads/thread), ensure tile0 landed
#pragma unroll
  for (int s = 0; s < 3; ++s) {
    STAGE_HALF(s, 0, 0); STAGE_HALF(s, 0, 1);
    STAGE_HALF(s, 1, 0); STAGE_HALF(s, 1, 1);
  }
  asm volatile("s_waitcnt vmcnt(8)");
  __builtin_amdgcn_s_barrier();
  __builtin_amdgcn_sched_barrier(0);

  short8 af[4], bfv[4];
  for (int t = 0; t < NK; ++t) {
    int bt = t & 3;
    // ---- phase 1: A mi0-3 + B, stage A halves of tile t+3 ----
#pragma unroll
    for (int i = 0; i < 4; ++i)
      af[i] = *(const short8*)&sT[bt][0][wr][(i * 16 + l16) * 32 + quad * 8];
#pragma unroll
    for (int i = 0; i < 4; ++i)
      bfv[i] = *(const short8*)&sT[bt][1][bhalf][(brow0 + i * 16 + l16) * 32 + quad * 8];
    if (t + 3 < NK) { STAGE_HALF(t + 3, 0, 0); STAGE_HALF(t + 3, 0, 1); }
    __builtin_amdgcn_s_barrier();
    __builtin_amdgcn_sched_barrier(0);
    __builtin_amdgcn_s_setprio(1);
#pragma unroll
    for (int mi = 0; mi < 4; ++mi)
#pragma unroll
      for (int ni = 0; ni < 4; ++ni)
        acc[mi][ni] = __builtin_amdgcn_mfma_f32_16x16x32_bf16(af[mi], bfv[ni], acc[mi][ni], 0, 0, 0);
    __builtin_amdgcn_s_setprio(0);
    __builtin_amdgcn_s_barrier();
    __builtin_amdgcn_sched_barrier(0);
    // ---- phase 2: A mi4-7, stage B halves of tile t+3, validate tile t+1 ----
#pragma unroll
    for (int i = 0; i < 4; ++i)
      af[i] = *(const short8*)&sT[bt][0][wr][((4 + i) * 16 + l16) * 32 + quad * 8];
    if (t + 3 < NK) { STAGE_HALF(t + 3, 1, 0); STAGE_HALF(t + 3, 1, 1); }
    // counted vmcnt: allow tiles t+2,t+3 stagings (4 loads each) to stay in flight
    if (t + 3 < NK)      asm volatile("s_waitcnt vmcnt(8)");
    else if (t + 2 < NK) asm volatile("s_waitcnt vmcnt(4)");
    else                 asm volatile("s_waitcnt vmcnt(0)");
    __builtin_amdgcn_s_barrier();
    __builtin_amdgcn_sched_barrier(0);
    __builtin_amdgcn_s_setprio(1);
#pragma unroll
    for (int mi = 0; mi < 4; ++mi)
#pragma unroll
      for (int ni = 0; ni < 4; ++ni)
        acc[4 + mi][ni] = __builtin_amdgcn_mfma_f32_16x16x32_bf16(af[mi], bfv[ni], acc[4 + mi][ni], 0, 0, 0);
    __builtin_amdgcn_s_setprio(0);
    __builtin_amdgcn_s_barrier();
    __builtin_amdgcn_sched_barrier(0);
  }
#undef STAGE_HALF

  if constexpr (EPI == 5) {
    // per-row max over this wave's 64 cols
#pragma unroll
    for (int mi = 0; mi < 8; ++mi)
#pragma unroll
      for (int r = 0; r < 4; ++r) {
        int rr = wr * 128 + mi * 16 + quad * 4 + r;
        float lm = -3.4e38f;
#pragma unroll
        for (int ni = 0; ni < 4; ++ni) lm = fmaxf(lm, acc[mi][ni][r]);
#pragma unroll
        for (int o = 1; o < 16; o <<= 1) lm = fmaxf(lm, __shfl_xor(lm, o));
        if (l16 == 0) smax[rr][wc] = lm;
      }
    __syncthreads();
#pragma unroll
    for (int mi = 0; mi < 8; ++mi)
#pragma unroll
      for (int r = 0; r < 4; ++r) {
        int rr = wr * 128 + mi * 16 + quad * 4 + r;
        float m = fmaxf(fmaxf(smax[rr][0], smax[rr][1]), fmaxf(smax[rr][2], smax[rr][3]));
        float ls = 0.f;
#pragma unroll
        for (int ni = 0; ni < 4; ++ni) ls += __expf(acc[mi][ni][r] - m);
#pragma unroll
        for (int o = 1; o < 16; o <<= 1) ls += __shfl_xor(ls, o);
        if (l16 == 0) ssum[rr][wc] = ls;
      }
    __syncthreads();
    if (tid < 256) {
      float m = fmaxf(fmaxf(smax[tid][0], smax[tid][1]), fmaxf(smax[tid][2], smax[tid][3]));
      float s = ssum[tid][0] + ssum[tid][1] + ssum[tid][2] + ssum[tid][3];
      tmax[(size_t)(bm + tid) * NT_ + bnT] = m;
      tsum[(size_t)(bm + tid) * NT_ + bnT] = s;
    }
  } else {
    ushort* C = (ushort*)Cv + (size_t)batch * Cbatch;
#pragma unroll
    for (int mi = 0; mi < 8; ++mi) {
      int row0 = bm + wr * 128 + mi * 16 + quad * 4;
#pragma unroll
      for (int ni = 0; ni < 4; ++ni) {
        int col = bn + wc * 64 + ni * 16 + l16;
#pragma unroll
        for (int r = 0; r < 4; ++r)
          C[(size_t)(row0 + r) * Crow + col] = f2bf(acc[mi][ni][r]);
      }
    }
  }
}

__global__ __launch_bounds__(256) void vocab_combine_kernel(const float* __restrict__ tmax,
                                                            const float* __restrict__ tsum,
                                                            float* __restrict__ rmax,
                                                            float* __restrict__ rsum) {
  __shared__ float sred[4];
  int m = blockIdx.x;
  float mx = -3.4e38f;
  for (int t = threadIdx.x; t < NT_; t += 256) mx = fmaxf(mx, tmax[(size_t)m * NT_ + t]);
  mx = block_reduce_max(mx, sred);
  float s = 0.f;
  for (int t = threadIdx.x; t < NT_; t += 256)
    s += tsum[(size_t)m * NT_ + t] * expf(tmax[(size_t)m * NT_ + t] - mx);
  s = block_reduce_sum(s, sred);
  if (threadIdx.x == 0) { rmax[m] = mx; rsum[m] = s; }
}

__global__ __launch_bounds__(256) void tlogit_kernel(const ushort* __restrict__ headout,
                                                     const ushort* __restrict__ emb,
                                                     const int* __restrict__ tgt,
                                                     float* __restrict__ tl) {
  __shared__ float sred[4];
  int m = blockIdx.x;
  int s = m >> 3, b = m & 7;
  int t = tgt[b * S_ + s];
  const ushort* a = headout + (size_t)m * 2048;
  const ushort* w = emb + (size_t)t * D_;
  float acc = 0.f;
  for (int i = threadIdx.x; i < D_; i += 256) acc += bf2f(a[i]) * bf2f(w[i]);
  acc = block_reduce_sum(acc, sred);
  if (threadIdx.x == 0) tl[m] = acc;
}

// ---------------- fused self-attention, one block per (b,h) ----------------
__global__ __launch_bounds__(256) void attn1_fused_kernel(const ushort* __restrict__ heads,
                                                          const ushort* __restrict__ rkproj,
                                                          const float* __restrict__ rw,
                                                          const float* __restrict__ rr,
                                                          ushort* __restrict__ attnA) {
  __shared__ float score[128][129];   // 66 KB
  __shared__ ushort pP[128][136];     // 34.8 KB
  __shared__ ushort vT[64][136];      // 17.4 KB
  int bz = blockIdx.x;
  int b = bz >> 4, n = bz & 15;
  int tid = threadIdx.x, lane = tid & 63, wave = tid >> 6;
  int quad = lane >> 4, l16 = lane & 15;
  int wrow = wave * 32;

  // stage V transposed: vT[d][j]
  {
    int j = tid >> 1, dbase = (tid & 1) * 32;
    const ushort* src = heads + (size_t)(j * 8 + b) * 3072 + 2048 + n * 64 + dbase;
#pragma unroll
    for (int c8 = 0; c8 < 4; ++c8) {
      short8 v8 = *(const short8*)(src + c8 * 8);
#pragma unroll
      for (int cc = 0; cc < 8; ++cc) vT[dbase + c8 * 8 + cc][j] = (ushort)v8[cc];
    }
  }

  // Q fragments with biases
  short8 qrw[2][2], qrr[2][2];
#pragma unroll
  for (int mi = 0; mi < 2; ++mi) {
    int i = wrow + mi * 16 + l16;
    const ushort* qp = heads + (size_t)(i * 8 + b) * 3072 + n * 64;
#pragma unroll
    for (int kc = 0; kc < 2; ++kc) {
      int k0 = kc * 32 + quad * 8;
      short8 qv = *(const short8*)(qp + k0);
      short8 w, rv;
#pragma unroll
      for (int t = 0; t < 8; ++t) {
        float q = bf2f((ushort)qv[t]);
        w[t] = (short)f2bf(q + rw[n * 64 + k0 + t]);
        rv[t] = (short)f2bf(q + rr[n * 64 + k0 + t]);
      }
      qrw[mi][kc] = w; qrr[mi][kc] = rv;
    }
  }

  // pass 1: AC -> score LDS
  {
    f32x4 acc[2][8];
#pragma unroll
    for (int i = 0; i < 2; ++i)
#pragma unroll
      for (int j = 0; j < 8; ++j) { acc[i][j][0]=0.f; acc[i][j][1]=0.f; acc[i][j][2]=0.f; acc[i][j][3]=0.f; }
#pragma unroll
    for (int kc = 0; kc < 2; ++kc) {
      int k0 = kc * 32 + quad * 8;
      short8 kf[8];
#pragma unroll
      for (int ni = 0; ni < 8; ++ni) {
        int j = ni * 16 + l16;
        kf[ni] = *(const short8*)(heads + (size_t)(j * 8 + b) * 3072 + 1024 + n * 64 + k0);
      }
#pragma unroll
      for (int mi = 0; mi < 2; ++mi)
#pragma unroll
        for (int ni = 0; ni < 8; ++ni)
          acc[mi][ni] = __builtin_amdgcn_mfma_f32_16x16x32_bf16(qrw[mi][kc], kf[ni], acc[mi][ni], 0, 0, 0);
    }
#pragma unroll
    for (int mi = 0; mi < 2; ++mi)
#pragma unroll
      for (int ni = 0; ni < 8; ++ni)
#pragma unroll
        for (int r = 0; r < 4; ++r)
          score[wrow + mi * 16 + quad * 4 + r][ni * 16 + l16] = acc[mi][ni][r];
  }
  // pass 2: BD pre-shift, add into score with rel-shift mapping
  {
    f32x4 acc[2][8];
#pragma unroll
    for (int i = 0; i < 2; ++i)
#pragma unroll
      for (int j = 0; j < 8; ++j) { acc[i][j][0]=0.f; acc[i][j][1]=0.f; acc[i][j][2]=0.f; acc[i][j][3]=0.f; }
#pragma unroll
    for (int kc = 0; kc < 2; ++kc) {
      int k0 = kc * 32 + quad * 8;
      short8 rkf[8];
#pragma unroll
      for (int ni = 0; ni < 8; ++ni) {
        int jp = ni * 16 + l16;
        rkf[ni] = *(const short8*)(rkproj + (size_t)jp * 1024 + n * 64 + k0);
      }
#pragma unroll
      for (int mi = 0; mi < 2; ++mi)
#pragma unroll
        for (int ni = 0; ni < 8; ++ni)
          acc[mi][ni] = __builtin_amdgcn_mfma_f32_16x16x32_bf16(qrr[mi][kc], rkf[ni], acc[mi][ni], 0, 0, 0);
    }
#pragma unroll
    for (int mi = 0; mi < 2; ++mi)
#pragma unroll
      for (int r = 0; r < 4; ++r) {
        int i = wrow + mi * 16 + quad * 4 + r;
#pragma unroll
        for (int ni = 0; ni < 8; ++ni) {
          int jp = ni * 16 + l16;
          if (jp >= 127 - i) score[i][jp - 127 + i] += acc[mi][ni][r];
        }
      }
  }
  // softmax (rows owned by same wave): row = tid>>1, half cols each
  {
    int row = tid >> 1, halfc = (tid & 1) * 64;
    float mx = -3.4e38f;
    for (int c = halfc; c < halfc + 64; ++c) {
      float v = (c <= row) ? score[row][c] * SCALE_F : -3.4e38f;
      mx = fmaxf(mx, v);
    }
    mx = fmaxf(mx, __shfl_xor(mx, 1));
    float s = 0.f;
    for (int c = halfc; c < halfc + 64; ++c) {
      float e = (c <= row) ? __expf(score[row][c] * SCALE_F - mx) : 0.f;
      score[row][c] = e;
      s += e;
    }
    s += __shfl_xor(s, 1);
    float inv = 1.0f / s;
    for (int c = halfc; c < halfc + 64; ++c) pP[row][c] = f2bf(score[row][c] * inv);
  }
  __syncthreads();  // vT + pP ready for all
  // PV: O[i][d] = sum_j P[i][j] V[j][d]
  {
    f32x4 acc[2][4];
#pragma unroll
    for (int i = 0; i < 2; ++i)
#pragma unroll
      for (int j = 0; j < 4; ++j) { acc[i][j][0]=0.f; acc[i][j][1]=0.f; acc[i][j][2]=0.f; acc[i][j][3]=0.f; }
#pragma unroll
    for (int kc = 0; kc < 4; ++kc) {
      int k0 = kc * 32 + quad * 8;
      short8 pf[2], vf[4];
#pragma unroll
      for (int mi = 0; mi < 2; ++mi)
        pf[mi] = *(const short8*)&pP[wrow + mi * 16 + l16][k0];
#pragma unroll
      for (int ni = 0; ni < 4; ++ni)
        vf[ni] = *(const short8*)&vT[ni * 16 + l16][k0];
#pragma unroll
      for (int mi = 0; mi < 2; ++mi)
#pragma unroll
        for (int ni = 0; ni < 4; ++ni)
          acc[mi][ni] = __builtin_amdgcn_mfma_f32_16x16x32_bf16(pf[mi], vf[ni], acc[mi][ni], 0, 0, 0);
    }
#pragma unroll
    for (int mi = 0; mi < 2; ++mi)
#pragma unroll
      for (int r = 0; r < 4; ++r) {
        int i = wrow + mi * 16 + quad * 4 + r;
#pragma unroll
        for (int ni = 0; ni < 4; ++ni)
          attnA[(size_t)(i * 8 + b) * 1024 + n * 64 + ni * 16 + l16] = f2bf(acc[mi][ni][r]);
      }
  }
}

// ---------------- fused cross-attention (flash over 4 E-tiles), block per (b,h) --------
__global__ __launch_bounds__(256) void attn2_fused_kernel(const float* __restrict__ q0,
                                                          const float* __restrict__ q1,
                                                          const ushort* __restrict__ kvproj,
                                                          const float* __restrict__ mask,
                                                          ushort* __restrict__ attnA) {
  __shared__ ushort vT[64][136];
  __shared__ ushort pP[128][136];
  __shared__ float mtile[128];
  int bz = blockIdx.x;
  int b = bz >> 4, n = bz & 15;
  int tid = threadIdx.x, lane = tid & 63, wave = tid >> 6;
  int quad = lane >> 4, l16 = lane & 15;
  int wrow = wave * 32;
  // Q frags: q0+q1 (split-K halves), f32 -> bf16
  short8 qf[2][2];
#pragma unroll
  for (int mi = 0; mi < 2; ++mi) {
    int i = wrow + mi * 16 + l16;
    size_t base = (size_t)(i * 8 + b) * 1024 + n * 64;
#pragma unroll
    for (int kc = 0; kc < 2; ++kc) {
      int k0 = kc * 32 + quad * 8;
      short8 v;
#pragma unroll
      for (int t = 0; t < 8; ++t) v[t] = (short)f2bf(q0[base + k0 + t] + q1[base + k0 + t]);
      qf[mi][kc] = v;
    }
  }
  float m_run[2][4], l_run[2][4];
#pragma unroll
  for (int mi = 0; mi < 2; ++mi)
#pragma unroll
    for (int r = 0; r < 4; ++r) { m_run[mi][r] = -3.0e38f; l_run[mi][r] = 0.f; }
  f32x4 accO[2][4];
#pragma unroll
  for (int i = 0; i < 2; ++i)
#pragma unroll
    for (int j = 0; j < 4; ++j) { accO[i][j][0]=0.f; accO[i][j][1]=0.f; accO[i][j][2]=0.f; accO[i][j][3]=0.f; }

  for (int et = 0; et < 4; ++et) {
    __syncthreads();  // previous tile's PV done before restaging
    // stage V2 tile transposed + mask tile
    {
      int j = tid >> 1, dbase = (tid & 1) * 32;
      int e = et * 128 + j;
      const ushort* src = kvproj + (size_t)(e * 8 + b) * 2048 + 1024 + n * 64 + dbase;
#pragma unroll
      for (int c8 = 0; c8 < 4; ++c8) {
        short8 v8 = *(const short8*)(src + c8 * 8);
#pragma unroll
        for (int cc = 0; cc < 8; ++cc) vT[dbase + c8 * 8 + cc][j] = (ushort)v8[cc];
      }
      if (tid < 128) mtile[tid] = (1.0f - mask[b * E_ + et * 128 + tid]) * NEGV;
    }
    // S tile
    f32x4 accS[2][8];
#pragma unroll
    for (int i = 0; i < 2; ++i)
#pragma unroll
      for (int j = 0; j < 8; ++j) { accS[i][j][0]=0.f; accS[i][j][1]=0.f; accS[i][j][2]=0.f; accS[i][j][3]=0.f; }
#pragma unroll
    for (int kc = 0; kc < 2; ++kc) {
      int k0 = kc * 32 + quad * 8;
      short8 kf[8];
#pragma unroll
      for (int ni = 0; ni < 8; ++ni) {
        int e = et * 128 + ni * 16 + l16;
        kf[ni] = *(const short8*)(kvproj + (size_t)(e * 8 + b) * 2048 + n * 64 + k0);
      }
#pragma unroll
      for (int mi = 0; mi < 2; ++mi)
#pragma unroll
        for (int ni = 0; ni < 8; ++ni)
          accS[mi][ni] = __builtin_amdgcn_mfma_f32_16x16x32_bf16(qf[mi][kc], kf[ni], accS[mi][ni], 0, 0, 0);
    }
    __syncthreads();  // vT, mtile ready
    // online softmax per owned row
#pragma unroll
    for (int mi = 0; mi < 2; ++mi)
#pragma unroll
      for (int r = 0; r < 4; ++r) {
        float v[8];
        float vmax = -3.4e38f;
#pragma unroll
        for (int ni = 0; ni < 8; ++ni) {
          v[ni] = accS[mi][ni][r] * SCALE_F + mtile[ni * 16 + l16];
          vmax = fmaxf(vmax, v[ni]);
        }
#pragma unroll
        for (int o = 1; o < 16; o <<= 1) vmax = fmaxf(vmax, __shfl_xor(vmax, o));
        float mnew = fmaxf(m_run[mi][r], vmax);
        float alpha = __expf(m_run[mi][r] - mnew);
        float ls = 0.f;
        int row = wrow + mi * 16 + quad * 4 + r;
#pragma unroll
        for (int ni = 0; ni < 8; ++ni) {
          float p = __expf(v[ni] - mnew);
          ls += p;
          pP[row][ni * 16 + l16] = f2bf(p);
        }
#pragma unroll
        for (int o = 1; o < 16; o <<= 1) ls += __shfl_xor(ls, o);
        l_run[mi][r] = l_run[mi][r] * alpha + ls;
        m_run[mi][r] = mnew;
#pragma unroll
        for (int ni = 0; ni < 4; ++ni) accO[mi][ni][r] *= alpha;
      }
    // PV accumulate (pP rows own-wave, vT via sync above)
#pragma unroll
    for (int kc = 0; kc < 4; ++kc) {
      int k0 = kc * 32 + quad * 8;
      short8 pf[2], vf[4];
#pragma unroll
      for (int mi = 0; mi < 2; ++mi)
        pf[mi] = *(const short8*)&pP[wrow + mi * 16 + l16][k0];
#pragma unroll
      for (int ni = 0; ni < 4; ++ni)
        vf[ni] = *(const short8*)&vT[ni * 16 + l16][k0];
#pragma unroll
      for (int mi = 0; mi < 2; ++mi)
#pragma unroll
        for (int ni = 0; ni < 4; ++ni)
          accO[mi][ni] = __builtin_amdgcn_mfma_f32_16x16x32_bf16(pf[mi], vf[ni], accO[mi][ni], 0, 0, 0);
    }
  }
  // finalize
#pragma unroll
  for (int mi = 0; mi < 2; ++mi)
#pragma unroll
    for (int r = 0; r < 4; ++r) {
      int i = wrow + mi * 16 + quad * 4 + r;
      float inv = 1.0f / l_run[mi][r];
#pragma unroll
      for (int ni = 0; ni < 4; ++ni)
        attnA[(size_t)(i * 8 + b) * 1024 + n * 64 + ni * 16 + l16] = f2bf(accO[mi][ni][r] * inv);
    }
}

// ---------------- add + layernorm with split-sum + optional bias ----------------
__global__ __launch_bounds__(256) void addln_kernel(const float* __restrict__ a,
                                                    const float* __restrict__ c,
                                                    int nsplit, long long cstride,
                                                    const float* __restrict__ bias,
                                                    const float* __restrict__ g,
                                                    const float* __restrict__ bb,
                                                    float* __restrict__ out,
                                                    ushort* __restrict__ out_bf) {
  __shared__ float sred[4];
  int row = blockIdx.x;
  const float* pa = a + (size_t)row * D_;
  float vals[4];
  float s = 0.f;
#pragma unroll
  for (int it = 0; it < 4; ++it) {
    int idx = threadIdx.x + it * 256;
    float v = pa[idx];
    for (int sp = 0; sp < nsplit; ++sp) v += c[(size_t)sp * cstride + (size_t)row * D_ + idx];
    if (bias) v += bias[idx];
    vals[it] = v;
    s += v;
  }
  s = block_reduce_sum(s, sred);
  float mean = s * (1.0f / D_);
  float ss = 0.f;
#pragma unroll
  for (int it = 0; it < 4; ++it) {
    float dd = vals[it] - mean;
    ss += dd * dd;
  }
  ss = block_reduce_sum(ss, sred);
  float inv = rsqrtf(ss * (1.0f / D_) + 1e-5f);
#pragma unroll
  for (int it = 0; it < 4; ++it) {
    int idx = threadIdx.x + it * 256;
    float r = (vals[it] - mean) * inv * g[idx] + bb[idx];
    out[(size_t)row * D_ + idx] = r;
    out_bf[(size_t)row * D_ + idx] = f2bf(r);
  }
}

__global__ __launch_bounds__(256) void mode_kernel(const float* __restrict__ core,
                                                   const float* __restrict__ mode_w,
                                                   const float* __restrict__ mode_b,
                                                   float* __restrict__ mode_sig) {
  __shared__ float sred[4];
  int m = blockIdx.x;
  const float* a = core + (size_t)m * D_;
  float s = 0.f;
  for (int t = threadIdx.x; t < D_; t += 256) s += a[t] * mode_w[t];
  s = block_reduce_sum(s, sred);
  if (threadIdx.x == 0) mode_sig[m] = 1.0f / (1.0f + expf(-(s + mode_b[0])));
}

// ---------------- final: copy attention + loss ----------------
__global__ __launch_bounds__(256) void final_kernel(const float* __restrict__ lg,
                                                    const int* __restrict__ ids,
                                                    const float* __restrict__ mask,
                                                    const int* __restrict__ tgt,
                                                    const float* __restrict__ mode_sig,
                                                    const float* __restrict__ tlogit,
                                                    const float* __restrict__ rmax,
                                                    const float* __restrict__ rsum,
                                                    float* __restrict__ loss_acc) {
  __shared__ float sred[4];
  int s = blockIdx.x, b = blockIdx.y;
  int m = s * B_ + b;
  size_t base = (size_t)(b * S_ + s) * E_;
  const long long LGS = (long long)B_ * S_ * E_;
  int tg = tgt[b * S_ + s];
  float lv[2];
  float mx = -3.4e38f;
#pragma unroll
  for (int it = 0; it < 2; ++it) {
    int e = threadIdx.x + it * 256;
    float raw = 0.f;
#pragma unroll
    for (int sp = 0; sp < 4; ++sp) raw += lg[sp * LGS + base + e];
    raw += (1.0f - mask[b * E_ + e]) * NEGV;
    lv[it] = raw;
    mx = fmaxf(mx, raw);
  }
  mx = block_reduce_max(mx, sred);
  float ssum = 0.f, csum = 0.f;
#pragma unroll
  for (int it = 0; it < 2; ++it) {
    int e = threadIdx.x + it * 256;
    float ev = expf(lv[it] - mx);
    ssum += ev;
    if (ids[b * E_ + e] == tg) csum += ev;
  }
  ssum = block_reduce_sum(ssum, sred);
  csum = block_reduce_sum(csum, sred);
  if (threadIdx.x == 0) {
    float copy_p = csum / ssum;
    float pv = expf(tlogit[m] - rmax[m]) / rsum[m];
    float msig = mode_sig[m];
    float predict = pv * msig + (1.0f - msig) * copy_p;
    float valid = (tg != 0) ? 1.0f : 0.0f;
    atomicAdd(&loss_acc[0], -logf(predict + 1e-6f) * valid);
    atomicAdd(&loss_acc[1], valid);
  }
}

__global__ void writeout_kernel(const float* __restrict__ loss_acc, float* __restrict__ out) {
  if (threadIdx.x < B_) out[threadIdx.x] = loss_acc[0] / loss_acc[1];
}

// ---------------- host ----------------
static void gw(hipStream_t st, int epi, const ushort* A, const ushort* B, const float* bias,
               void* C, int M, int N, int K,
               long long Ar, long long Ab, long long Br, long long Bb,
               long long Cr, long long Cb, int nb, int ksplit, long long Csplit) {
  dim3 g(N / 128, M / 128, nb * ksplit);
  switch (epi) {
    case 0: gemm_w_kernel<0><<<g, 256, 0, st>>>(A, B, bias, C, M, N, K, ksplit, Ar, Ab, Br, Bb, Cr, Cb, Csplit); break;
    case 1: gemm_w_kernel<1><<<g, 256, 0, st>>>(A, B, bias, C, M, N, K, ksplit, Ar, Ab, Br, Bb, Cr, Cb, Csplit); break;
    case 3: gemm_w_kernel<3><<<g, 256, 0, st>>>(A, B, bias, C, M, N, K, ksplit, Ar, Ab, Br, Bb, Cr, Cb, Csplit); break;
    case 4: gemm_w_kernel<4><<<g, 256, 0, st>>>(A, B, bias, C, M, N, K, ksplit, Ar, Ab, Br, Bb, Cr, Cb, Csplit); break;
  }
}
static void castTo(hipStream_t st, const float* src, ushort* dst, size_t count) {
  int n4 = (int)(count / 4);
  castf_kernel<<<(n4 + 255) / 256, 256, 0, st>>>(src, dst, n4);
}

extern "C" void kernel_launch(void* const* d_in, const int* in_sizes, int n_in,
                              void* d_out, int out_size, void* d_ws, size_t ws_size,
                              hipStream_t stream) {
  const int* input_ids = (const int*)d_in[0];
  const float* encoder_rep = (const float*)d_in[1];
  const float* input_mask = (const float*)d_in[2];
  const int* decode_input = (const int*)d_in[3];
  const int* decode_target = (const int*)d_in[4];
  const float* word_emb = (const float*)d_in[5];
  const float* qkv_w = (const float*)d_in[6];
  const float* r_w = (const float*)d_in[7];
  const float* o_w = (const float*)d_in[8];
  const float* kv_w = (const float*)d_in[9];
  const float* q_w = (const float*)d_in[10];
  const float* io_w = (const float*)d_in[11];
  const float* rr_bias = (const float*)d_in[12];
  const float* rw_bias = (const float*)d_in[13];
  const float* ln1_g = (const float*)d_in[14];
  const float* ln1_b = (const float*)d_in[15];
  const float* ln2_g = (const float*)d_in[16];
  const float* ln2_b = (const float*)d_in[17];
  const float* ffn_w1 = (const float*)d_in[18];
  const float* ffn_b1 = (const float*)d_in[19];
  const float* ffn_w2 = (const float*)d_in[20];
  const float* ffn_b2 = (const float*)d_in[21];
  const float* ln3_g = (const float*)d_in[22];
  const float* ln3_b = (const float*)d_in[23];
  const float* out_w = (const float*)d_in[24];
  const float* out_b = (const float*)d_in[25];
  const float* copy_w = (const float*)d_in[26];
  const float* copy_b = (const float*)d_in[27];
  const float* mode_w = (const float*)d_in[28];
  const float* mode_b = (const float*)d_in[29];
  float* out = (float*)d_out;

  char* base = (char*)d_ws;
  size_t off = 0;
  auto alloc = [&](size_t bytes) -> void* {
    void* p = base + off;
    off = (off + bytes + 255) & ~(size_t)255;
    return p;
  };

  // per-layer weight buffers (cast each layer, merged into one dispatch)
  ushort* wl_qkv = (ushort*)alloc((size_t)3 * D_ * D_ * 2);
  ushort* wl_o = (ushort*)alloc((size_t)D_ * D_ * 2);
  ushort* wl_q = (ushort*)alloc((size_t)D_ * D_ * 2);
  ushort* wl_io = (ushort*)alloc((size_t)D_ * D_ * 2);
  ushort* wl_f1 = (ushort*)alloc((size_t)FF_ * D_ * 2);
  ushort* wl_f2 = (ushort*)alloc((size_t)FF_ * D_ * 2);
  // hoisted all-layer buffers (encoder-side work batched upfront)
  ushort* wl_kv = (ushort*)alloc((size_t)L_ * 2 * D_ * D_ * 2);
  ushort* wl_r = (ushort*)alloc((size_t)L_ * D_ * D_ * 2);
  ushort* kvproj_bf = (ushort*)alloc((size_t)L_ * ME_ * 2 * D_ * 2);
  ushort* rkproj_bf = (ushort*)alloc((size_t)L_ * S_ * D_ * 2);

  ushort* w_emb = (ushort*)alloc((size_t)V_ * D_ * 2);
  ushort* w_oc = (ushort*)alloc((size_t)2048 * D_ * 2);
  float* b_oc = (float*)alloc(2048 * 4);
  ushort* enc_bf = (ushort*)alloc((size_t)ME_ * D_ * 2);
  ushort* encT_bf = (ushort*)alloc((size_t)ME_ * D_ * 2);
  ushort* r_bf = (ushort*)alloc((size_t)S_ * D_ * 2);
  float* f_core = (float*)alloc((size_t)M_ * D_ * 4);
  ushort* core_bf = (ushort*)alloc((size_t)M_ * D_ * 2);
  ushort* heads_bf = (ushort*)alloc((size_t)M_ * 3 * D_ * 2);
  ushort* attnA_bf = (ushort*)alloc((size_t)M_ * D_ * 2);
  float* f_tmp = (float*)alloc((size_t)4 * M_ * D_ * 4);   // up to 4 split buffers
  float* f_x = (float*)alloc((size_t)M_ * D_ * 4);
  ushort* x_bf = (ushort*)alloc((size_t)M_ * D_ * 2);
  float* f_y = (float*)alloc((size_t)M_ * D_ * 4);
  ushort* y_bf = (ushort*)alloc((size_t)M_ * D_ * 2);
  float* f_q = (float*)alloc((size_t)2 * M_ * D_ * 4);      // q split buffers
  ushort* ffnh_bf = (ushort*)alloc((size_t)M_ * FF_ * 2);
  ushort* headout_bf = (ushort*)alloc((size_t)M_ * 2048 * 2);
  float* f_lg = (float*)alloc((size_t)4 * B_ * S_ * E_ * 4);
  float* f_tmax = (float*)alloc((size_t)M_ * NT_ * 4);
  float* f_tsum = (float*)alloc((size_t)M_ * NT_ * 4);
  float* f_rmax = (float*)alloc(M_ * 4);
  float* f_rsum = (float*)alloc(M_ * 4);
  float* f_tlogit = (float*)alloc(M_ * 4);
  float* f_mode = (float*)alloc(M_ * 4);
  float* f_loss = (float*)alloc(64);

  // global casts + setup
  castTo(stream, word_emb, w_emb, (size_t)V_ * D_);
  castTo(stream, out_w, w_oc, (size_t)D_ * D_);
  castTo(stream, copy_w, w_oc + (size_t)D_ * D_, (size_t)D_ * D_);
  hipMemcpyAsync(b_oc, out_b, D_ * 4, hipMemcpyDeviceToDevice, stream);
  hipMemcpyAsync(b_oc + D_, copy_b, D_ * 4, hipMemcpyDeviceToDevice, stream);
  castTo(stream, encoder_rep, enc_bf, (size_t)ME_ * D_);
  enct_kernel<<<(ME_ * D_) / 256, 256, 0, stream>>>(encoder_rep, encT_bf);
  pos_emb_kernel<<<(S_ * D_ + 255) / 256, 256, 0, stream>>>(r_bf);
  embed_kernel<<<(M_ * D_) / 256, 256, 0, stream>>>(decode_input, word_emb, f_core, core_bf);

  // hoisted: all-layer kv/r weight casts + batched encoder-side projections
  castTo(stream, kv_w, wl_kv, (size_t)L_ * 2 * D_ * D_);
  castTo(stream, r_w, wl_r, (size_t)L_ * D_ * D_);
  // kvproj[l] = encT @ kv_w[l]^T : 256^2 deep-pipelined, batched over layers
  gemm256_kernel<1><<<dim3(2 * D_ / 256, ME_ / 256, L_), 512, 0, stream>>>(
      encT_bf, wl_kv, kvproj_bf, nullptr, nullptr,
      D_, 0, D_, (long long)2 * D_ * D_, 2 * D_, (long long)ME_ * 2 * D_);
  // rkproj[l] = r @ r_w[l]^T : batched over layers (32 blocks, small)
  gw(stream, 1, r_bf, wl_r, nullptr, rkproj_bf, S_, D_, D_,
     D_, 0, D_, (long long)D_ * D_, D_, (long long)S_ * D_, L_, 1, 0);

  for (int l = 0; l < L_; ++l) {
    // one merged cast for this layer's decoder-side weights
    castlayer_kernel<<<14336, 256, 0, stream>>>(
        qkv_w + (size_t)l * 3 * D_ * D_, o_w + (size_t)l * D_ * D_,
        q_w + (size_t)l * D_ * D_, io_w + (size_t)l * D_ * D_,
        ffn_w1 + (size_t)l * FF_ * D_, ffn_w2 + (size_t)l * FF_ * D_,
        wl_qkv, wl_o, wl_q, wl_io, wl_f1, wl_f2);

    // self-attention
    gw(stream, 1, core_bf, wl_qkv, nullptr, heads_bf, M_, 3 * D_, D_, D_, 0, D_, 0, 3 * D_, 0, 1, 1, 0);
    attn1_fused_kernel<<<B_ * H_, 256, 0, stream>>>(heads_bf, rkproj_bf + (size_t)l * S_ * D_,
                                                    rw_bias + (size_t)l * D_,
                                                    rr_bias + (size_t)l * D_, attnA_bf);
    gw(stream, 0, attnA_bf, wl_o, nullptr, f_tmp, M_, D_, D_, D_, 0, D_, 0, D_, 0, 1, 2,
       (long long)M_ * D_);
    addln_kernel<<<M_, 256, 0, stream>>>(f_core, f_tmp, 2, (long long)M_ * D_, nullptr,
                                         ln1_g + (size_t)l * D_, ln1_b + (size_t)l * D_, f_x, x_bf);

    // cross-attention (kvproj precomputed upfront)
    gw(stream, 0, x_bf, wl_q, nullptr, f_q, M_, D_, D_, D_, 0, D_, 0, D_, 0, 1, 2,
       (long long)M_ * D_);
    attn2_fused_kernel<<<B_ * H_, 256, 0, stream>>>(f_q, f_q + (size_t)M_ * D_,
                                                    kvproj_bf + (size_t)l * ME_ * 2 * D_,
                                                    input_mask, attnA_bf);
    gw(stream, 0, attnA_bf, wl_io, nullptr, f_tmp, M_, D_, D_, D_, 0, D_, 0, D_, 0, 1, 2,
       (long long)M_ * D_);
    addln_kernel<<<M_, 256, 0, stream>>>(f_x, f_tmp, 2, (long long)M_ * D_, nullptr,
                                         ln2_g + (size_t)l * D_, ln2_b + (size_t)l * D_, f_y, y_bf);

    // FFN
    gw(stream, 4, y_bf, wl_f1, ffn_b1 + (size_t)l * FF_, ffnh_bf, M_, FF_, D_, D_, 0, D_, 0, FF_, 0, 1, 1, 0);
    gw(stream, 0, ffnh_bf, wl_f2, nullptr, f_tmp, M_, D_, FF_, FF_, 0, FF_, 0, D_, 0, 1, 4,
       (long long)M_ * D_);
    addln_kernel<<<M_, 256, 0, stream>>>(f_y, f_tmp, 4, (long long)M_ * D_,
                                         ffn_b2 + (size_t)l * D_,
                                         ln3_g + (size_t)l * D_, ln3_b + (size_t)l * D_, f_core, core_bf);
  }

  // merged output+copy head GEMM: [M,2048]
  gw(stream, 3, core_bf, w_oc, b_oc, headout_bf, M_, 2048, D_, D_, 0, D_, 0, 2048, 0, 1, 1, 0);
  mode_kernel<<<M_, 256, 0, stream>>>(f_core, mode_w, mode_b, f_mode);

  // vocab softmax stats: 256^2 deep-pipelined + fused stats epilogue (500 blocks)
  gemm256_kernel<5><<<500, 512, 0, stream>>>(headout_bf, w_emb, nullptr, f_tmax, f_tsum,
                                             2048, 0, D_, 0, 0, 0);
  vocab_combine_kernel<<<M_, 256, 0, stream>>>(f_tmax, f_tsum, f_rmax, f_rsum);
  tlogit_kernel<<<M_, 256, 0, stream>>>(headout_bf, w_emb, decode_target, f_tlogit);

  // copy logits: batched over b, split-K 4
  gw(stream, 0, headout_bf + D_, enc_bf, nullptr, f_lg, S_, E_, D_,
     (long long)B_ * 2048, 2048, D_, (long long)E_ * D_, E_, (long long)S_ * E_, B_, 4,
     (long long)B_ * S_ * E_);

  hipMemsetAsync(f_loss, 0, 2 * sizeof(float), stream);
  final_kernel<<<dim3(S_, B_), 256, 0, stream>>>(f_lg, input_ids, input_mask, decode_target,
                                                 f_mode, f_tlogit, f_rmax, f_rsum, f_loss);
  writeout_kernel<<<1, 64, 0, stream>>>(f_loss, out);
}

// Round 3
// 1573.375 us; speedup vs baseline: 1.1116x; 1.0094x over previous
//
#include <hip/hip_runtime.h>
#include <math.h>

#define B_ 8
#define S_ 128
#define E_ 512
#define D_ 1024
#define H_ 16
#define L_ 4
#define V_ 32000
#define DH_ 64
#define FF_ 4096
#define M_ 1024      // S_*B_ rows, row = s*B_+b
#define ME_ 4096     // E_*B_ rows, row = e*B_+b
#define NT_ 125      // V_/256 vocab tiles
#define SCALE_F 0.125f
#define NEGV (-1e30f)

typedef __attribute__((ext_vector_type(8))) short short8;
typedef __attribute__((ext_vector_type(4))) float f32x4;

// ---------------- helpers ----------------
__device__ __forceinline__ float bf2f(ushort u) {
  union { unsigned int u32; float f; } v; v.u32 = ((unsigned int)u) << 16; return v.f;
}
__device__ __forceinline__ ushort f2bf(float x) {
  union { float f; unsigned int u; } v; v.f = x;
  unsigned int r = v.u + 0x7fff + ((v.u >> 16) & 1);
  return (ushort)(r >> 16);
}
__device__ __forceinline__ void gl_lds16(const ushort* g, ushort* l) {
  __builtin_amdgcn_global_load_lds((const __attribute__((address_space(1))) void*)g,
                                   (__attribute__((address_space(3))) void*)l, 16, 0, 0);
}

__device__ __forceinline__ float warp_reduce_sum(float v) {
#pragma unroll
  for (int o = 32; o > 0; o >>= 1) v += __shfl_down(v, o);
  return v;
}
__device__ __forceinline__ float warp_reduce_max(float v) {
#pragma unroll
  for (int o = 32; o > 0; o >>= 1) v = fmaxf(v, __shfl_down(v, o));
  return v;
}
__device__ __forceinline__ float block_reduce_sum(float v, float* sred) {
  v = warp_reduce_sum(v);
  __syncthreads();
  if ((threadIdx.x & 63) == 0) sred[threadIdx.x >> 6] = v;
  __syncthreads();
  float s = 0.0f;
  int nw = blockDim.x >> 6;
  for (int w = 0; w < nw; ++w) s += sred[w];
  return s;
}
__device__ __forceinline__ float block_reduce_max(float v, float* sred) {
  v = warp_reduce_max(v);
  __syncthreads();
  if ((threadIdx.x & 63) == 0) sred[threadIdx.x >> 6] = v;
  __syncthreads();
  float s = -3.4e38f;
  int nw = blockDim.x >> 6;
  for (int w = 0; w < nw; ++w) s = fmaxf(s, sred[w]);
  return s;
}

// ---------------- cast / setup ----------------
__global__ __launch_bounds__(256) void castf_kernel(const float* __restrict__ in,
                                                    ushort* __restrict__ out, int n4) {
  int t = blockIdx.x * 256 + threadIdx.x;
  if (t >= n4) return;
  float4 v = ((const float4*)in)[t];
  ushort4 o;
  o.x = f2bf(v.x); o.y = f2bf(v.y); o.z = f2bf(v.z); o.w = f2bf(v.w);
  ((ushort4*)out)[t] = o;
}

// merged per-layer weight cast: qkv(3D^2) | o(D^2) | q(D^2) | io(D^2) | f1(4D^2) | f2(4D^2)
__global__ __launch_bounds__(256) void castlayer_kernel(
    const float* __restrict__ sqkv, const float* __restrict__ so,
    const float* __restrict__ sq, const float* __restrict__ sio,
    const float* __restrict__ sf1, const float* __restrict__ sf2,
    ushort* __restrict__ dqkv, ushort* __restrict__ dov,
    ushort* __restrict__ dq, ushort* __restrict__ dio,
    ushort* __restrict__ df1, ushort* __restrict__ df2) {
  int t = blockIdx.x * 256 + threadIdx.x;   // float4 index into concatenated segments
  const float* src; ushort* dst; int idx;
  if (t < 786432)       { src = sqkv; dst = dqkv; idx = t; }
  else if (t < 1048576) { src = so;  dst = dov; idx = t - 786432; }
  else if (t < 1310720) { src = sq;  dst = dq;  idx = t - 1048576; }
  else if (t < 1572864) { src = sio; dst = dio; idx = t - 1310720; }
  else if (t < 2621440) { src = sf1; dst = df1; idx = t - 1572864; }
  else if (t < 3670016) { src = sf2; dst = df2; idx = t - 2621440; }
  else return;
  float4 v = ((const float4*)src)[idx];
  ushort4 o4;
  o4.x = f2bf(v.x); o4.y = f2bf(v.y); o4.z = f2bf(v.z); o4.w = f2bf(v.w);
  ((ushort4*)dst)[idx] = o4;
}

// encoder_rep [b,e,d] -> bf16 linear (enc_bf) AND rows (e*B+b) (encT) in one pass
__global__ __launch_bounds__(256) void enc_both_kernel(const float* __restrict__ enc,
                                                       ushort* __restrict__ enc_bf,
                                                       ushort* __restrict__ encT) {
  int t = blockIdx.x * 256 + threadIdx.x;
  if (t >= ME_ * D_) return;
  ushort bv = f2bf(enc[t]);
  enc_bf[t] = bv;
  int d = t & (D_ - 1);
  int be = t >> 10;                      // b*E_+e
  int b = be >> 9, e = be & (E_ - 1);    // E_ = 512
  encT[((size_t)(e * B_ + b) << 10) + d] = bv;
}

__global__ __launch_bounds__(256) void pos_emb_kernel(ushort* __restrict__ r) {
  int t = blockIdx.x * 256 + threadIdx.x;
  if (t >= S_ * D_) return;
  int i = t / D_, j = t % D_;
  float pos = (float)(S_ - 1 - i);
  int jj = (j < D_ / 2) ? j : (j - D_ / 2);
  float invf = powf(10000.0f, -(float)(2 * jj) / (float)D_);
  float a = pos * invf;
  r[t] = f2bf((j < D_ / 2) ? sinf(a) : cosf(a));
}

__global__ __launch_bounds__(256) void embed_kernel(const int* __restrict__ ids,
                                                    const float* __restrict__ emb,
                                                    float* __restrict__ core,
                                                    ushort* __restrict__ core_bf) {
  int t = blockIdx.x * 256 + threadIdx.x;
  if (t >= M_ * D_) return;
  int d = t & (D_ - 1);
  int row = t >> 10;
  int s = row >> 3, b = row & 7;
  float v = emb[(size_t)ids[b * S_ + s] * D_ + d];
  core[t] = v;
  core_bf[t] = f2bf(v);
}

// ---------------- bf16 MFMA GEMM, 128x128 tile, batched + split-K ----------------
// EPI: 0 f32, 1 bf16, 3 bf16+bias, 4 bf16+bias+gelu
template <int EPI>
__global__ __launch_bounds__(256) void gemm_w_kernel(
    const ushort* __restrict__ A, const ushort* __restrict__ Bm,
    const float* __restrict__ bias, void* __restrict__ Cv,
    int M, int N, int K, int ksplit,
    long long Arow, long long Abatch, long long Brow, long long Bbatch,
    long long Crow, long long Cbatch, long long Csplit) {
  __shared__ ushort lA[128 * 32];
  __shared__ ushort lB[128 * 32];
  int tid = threadIdx.x;
  int bz = blockIdx.z;
  int batch = bz / ksplit, split = bz % ksplit;
  int kLen = K / ksplit, kStart = split * kLen;
  const ushort* Ab = A + (size_t)batch * Abatch;
  const ushort* Bb = Bm + (size_t)batch * Bbatch;
  int bm = blockIdx.y * 128, bn = blockIdx.x * 128;
  int lane = tid & 63, wave = tid >> 6;
  int wrow = (wave >> 1) * 64, wcol = (wave & 1) * 64;
  int quad = lane >> 4, l16 = lane & 15;
  f32x4 acc[4][4];
#pragma unroll
  for (int i = 0; i < 4; ++i)
#pragma unroll
    for (int j = 0; j < 4; ++j) { acc[i][j][0] = 0.f; acc[i][j][1] = 0.f; acc[i][j][2] = 0.f; acc[i][j][3] = 0.f; }
  int r0 = tid >> 2, c0 = (tid & 3) * 8;
  int r1 = (tid + 256) >> 2;
  for (int k0 = kStart; k0 < kStart + kLen; k0 += 32) {
    __syncthreads();
    gl_lds16(Ab + (size_t)(bm + r0) * Arow + k0 + c0, &lA[(size_t)tid * 8]);
    gl_lds16(Ab + (size_t)(bm + r1) * Arow + k0 + c0, &lA[(size_t)(256 + tid) * 8]);
    gl_lds16(Bb + (size_t)(bn + r0) * Brow + k0 + c0, &lB[(size_t)tid * 8]);
    gl_lds16(Bb + (size_t)(bn + r1) * Brow + k0 + c0, &lB[(size_t)(256 + tid) * 8]);
    __syncthreads();
    short8 af[4], bfr[4];
#pragma unroll
    for (int mi = 0; mi < 4; ++mi)
      af[mi] = *(const short8*)&lA[(size_t)(wrow + mi * 16 + l16) * 32 + quad * 8];
#pragma unroll
    for (int ni = 0; ni < 4; ++ni)
      bfr[ni] = *(const short8*)&lB[(size_t)(wcol + ni * 16 + l16) * 32 + quad * 8];
#pragma unroll
    for (int mi = 0; mi < 4; ++mi)
#pragma unroll
      for (int ni = 0; ni < 4; ++ni)
        acc[mi][ni] = __builtin_amdgcn_mfma_f32_16x16x32_bf16(af[mi], bfr[ni], acc[mi][ni], 0, 0, 0);
  }
#pragma unroll
  for (int mi = 0; mi < 4; ++mi) {
    int row0 = bm + wrow + mi * 16 + quad * 4;
#pragma unroll
    for (int ni = 0; ni < 4; ++ni) {
      int col = bn + wcol + ni * 16 + l16;
      float bv = 0.f;
      if (EPI >= 3) bv = bias[col];
#pragma unroll
      for (int r = 0; r < 4; ++r) {
        float v = acc[mi][ni][r] + bv;
        if (EPI == 4) v = 0.5f * v * (1.0f + erff(v * 0.70710678118654752f));
        size_t ci = (size_t)split * Csplit + (size_t)batch * Cbatch + (size_t)(row0 + r) * Crow + col;
        if (EPI == 0) ((float*)Cv)[ci] = v;
        else ((ushort*)Cv)[ci] = f2bf(v);
      }
    }
  }
}

// ---------------- 256x256-tile deep-pipelined GEMM (BK=32, 4-deep LDS ring) ----------
// T2: XOR swizzle (slot ^= (row>>1)&3) applied on BOTH the global staging source and
// the ds_read side (rule #21: global_load_lds dest must stay linear). Kills the 8-way
// bank conflict of the 64B-row layout (lanes l16 even-rows previously shared a 4-bank
// group). T3+T4: counted vmcnt ring; T5: setprio around MFMA clusters.
// EPI 1: bf16 C store; EPI 5: vocab softmax-stats epilogue (XCD-bijective swizzle)
template <int EPI>
__global__ __launch_bounds__(512, 2) void gemm256_kernel(
    const ushort* __restrict__ A, const ushort* __restrict__ Bm, void* __restrict__ Cv,
    float* __restrict__ tmax, float* __restrict__ tsum,
    long long Arow, long long Abatch, long long Brow, long long Bbatch,
    long long Crow, long long Cbatch) {
  // [buf][A=0/B=1][half][128 rows x 32 cols] : 4 x 32KB = 128 KB
  __shared__ ushort sT[4][2][2][128 * 32];
  __shared__ float smax[256][4];
  __shared__ float ssum[256][4];
  const int NK = 32;  // K = 1024 = 32 K-tiles of BK=32
  int tid = threadIdx.x;
  int bm, bn, bnT = 0, batch = 0;
  if constexpr (EPI == 5) {
    // bijective m204 swizzle, nwg=500: q=62, r=4 (xcd<4 gets 63 blocks)
    int orig = blockIdx.x;
    int xcd = orig & 7;
    int base = (xcd < 4) ? xcd * 63 : 4 * 63 + (xcd - 4) * 62;
    int wg = base + (orig >> 3);
    bm = (wg & 3) * 256;          // row tile fast -> co-resident blocks share B panel
    bnT = wg >> 2;
    bn = bnT * 256;
  } else {
    bn = blockIdx.x * 256;
    bm = blockIdx.y * 256;
    batch = blockIdx.z;
  }
  const ushort* Ab = A + (size_t)batch * Abatch;
  const ushort* Bb = Bm + (size_t)batch * Bbatch;
  int lane = tid & 63, wave = tid >> 6;
  int wr = wave >> 2;          // 0..1 : row half (128 rows)
  int wc = wave & 3;           // 0..3 : col quarter (64 cols)
  int bhalf = wc >> 1;         // B half this wave reads
  int brow0 = (wc & 1) * 64;   // row base within B half
  int quad = lane >> 4, l16 = lane & 15;
  // staging coords with T2 source pre-swizzle (involution: slot ^ ((row>>1)&3))
  int sr = tid >> 2;
  int sslot = (((tid & 3) ^ ((sr >> 1) & 3)) * 8);
  // read-side swizzle (row = i*16+l16: (row>>1)&3 == (l16>>1)&3 for all frags)
  int rsw = (quad ^ ((l16 >> 1) & 3)) * 8;

  f32x4 acc[8][4];
#pragma unroll
  for (int i = 0; i < 8; ++i)
#pragma unroll
    for (int j = 0; j < 4; ++j) { acc[i][j][0]=0.f; acc[i][j][1]=0.f; acc[i][j][2]=0.f; acc[i][j][3]=0.f; }

  // stage one half-tile (1 gl_lds per thread): ab=0 A, ab=1 B; h = row-half
#define STAGE_HALF(s_, ab_, h_)                                                        \
  do {                                                                                 \
    int s__ = (s_); int b__ = s__ & 3;                                                 \
    if ((ab_) == 0)                                                                    \
      gl_lds16(Ab + (size_t)(bm + (h_) * 128 + sr) * Arow + s__ * 32 + sslot,          \
               &sT[b__][0][h_][tid * 8]);                                              \
    else                                                                               \
      gl_lds16(Bb + (size_t)(bn + (h_) * 128 + sr) * Brow + s__ * 32 + sslot,          \
               &sT[b__][1][h_][tid * 8]);                                              \
  } while (0)

  // prologue: stage tiles 0,1,2 (12 loads/thread), ensure tile0 landed
#pragma unroll
  for (int s = 0; s < 3; ++s) {
    STAGE_HALF(s, 0, 0); STAGE_HALF(s, 0, 1);
    STAGE_HALF(s, 1, 0); STAGE_HALF(s, 1, 1);
  }
  asm volatile("s_waitcnt vmcnt(8)");
  __builtin_amdgcn_s_barrier();
  __builtin_amdgcn_sched_barrier(0);

  short8 af[4], bfv[4];
  for (int t = 0; t < NK; ++t) {
    int bt = t & 3;
    // ---- phase 1: A mi0-3 + B, stage A halves of tile t+3 ----
#pragma unroll
    for (int i = 0; i < 4; ++i)
      af[i] = *(const short8*)&sT[bt][0][wr][(i * 16 + l16) * 32 + rsw];
#pragma unroll
    for (int i = 0; i < 4; ++i)
      bfv[i] = *(const short8*)&sT[bt][1][bhalf][(brow0 + i * 16 + l16) * 32 + rsw];
    if (t + 3 < NK) { STAGE_HALF(t + 3, 0, 0); STAGE_HALF(t + 3, 0, 1); }
    __builtin_amdgcn_s_barrier();
    __builtin_amdgcn_sched_barrier(0);
    __builtin_amdgcn_s_setprio(1);
#pragma unroll
    for (int mi = 0; mi < 4; ++mi)
#pragma unroll
      for (int ni = 0; ni < 4; ++ni)
        acc[mi][ni] = __builtin_amdgcn_mfma_f32_16x16x32_bf16(af[mi], bfv[ni], acc[mi][ni], 0, 0, 0);
    __builtin_amdgcn_s_setprio(0);
    __builtin_amdgcn_s_barrier();
    __builtin_amdgcn_sched_barrier(0);
    // ---- phase 2: A mi4-7, stage B halves of tile t+3, validate tile t+1 ----
#pragma unroll
    for (int i = 0; i < 4; ++i)
      af[i] = *(const short8*)&sT[bt][0][wr][((4 + i) * 16 + l16) * 32 + rsw];
    if (t + 3 < NK) { STAGE_HALF(t + 3, 1, 0); STAGE_HALF(t + 3, 1, 1); }
    // counted vmcnt: allow tiles t+2,t+3 stagings (4 loads each) to stay in flight
    if (t + 3 < NK)      asm volatile("s_waitcnt vmcnt(8)");
    else if (t + 2 < NK) asm volatile("s_waitcnt vmcnt(4)");
    else                 asm volatile("s_waitcnt vmcnt(0)");
    __builtin_amdgcn_s_barrier();
    __builtin_amdgcn_sched_barrier(0);
    __builtin_amdgcn_s_setprio(1);
#pragma unroll
    for (int mi = 0; mi < 4; ++mi)
#pragma unroll
      for (int ni = 0; ni < 4; ++ni)
        acc[4 + mi][ni] = __builtin_amdgcn_mfma_f32_16x16x32_bf16(af[mi], bfv[ni], acc[4 + mi][ni], 0, 0, 0);
    __builtin_amdgcn_s_setprio(0);
    __builtin_amdgcn_s_barrier();
    __builtin_amdgcn_sched_barrier(0);
  }
#undef STAGE_HALF

  if constexpr (EPI == 5) {
    // per-row max over this wave's 64 cols
#pragma unroll
    for (int mi = 0; mi < 8; ++mi)
#pragma unroll
      for (int r = 0; r < 4; ++r) {
        int rr = wr * 128 + mi * 16 + quad * 4 + r;
        float lm = -3.4e38f;
#pragma unroll
        for (int ni = 0; ni < 4; ++ni) lm = fmaxf(lm, acc[mi][ni][r]);
#pragma unroll
        for (int o = 1; o < 16; o <<= 1) lm = fmaxf(lm, __shfl_xor(lm, o));
        if (l16 == 0) smax[rr][wc] = lm;
      }
    __syncthreads();
#pragma unroll
    for (int mi = 0; mi < 8; ++mi)
#pragma unroll
      for (int r = 0; r < 4; ++r) {
        int rr = wr * 128 + mi * 16 + quad * 4 + r;
        float m = fmaxf(fmaxf(smax[rr][0], smax[rr][1]), fmaxf(smax[rr][2], smax[rr][3]));
        float ls = 0.f;
#pragma unroll
        for (int ni = 0; ni < 4; ++ni) ls += __expf(acc[mi][ni][r] - m);
#pragma unroll
        for (int o = 1; o < 16; o <<= 1) ls += __shfl_xor(ls, o);
        if (l16 == 0) ssum[rr][wc] = ls;
      }
    __syncthreads();
    if (tid < 256) {
      float m = fmaxf(fmaxf(smax[tid][0], smax[tid][1]), fmaxf(smax[tid][2], smax[tid][3]));
      float s = ssum[tid][0] + ssum[tid][1] + ssum[tid][2] + ssum[tid][3];
      tmax[(size_t)(bm + tid) * NT_ + bnT] = m;
      tsum[(size_t)(bm + tid) * NT_ + bnT] = s;
    }
  } else {
    ushort* C = (ushort*)Cv + (size_t)batch * Cbatch;
#pragma unroll
    for (int mi = 0; mi < 8; ++mi) {
      int row0 = bm + wr * 128 + mi * 16 + quad * 4;
#pragma unroll
      for (int ni = 0; ni < 4; ++ni) {
        int col = bn + wc * 64 + ni * 16 + l16;
#pragma unroll
        for (int r = 0; r < 4; ++r)
          C[(size_t)(row0 + r) * Crow + col] = f2bf(acc[mi][ni][r]);
      }
    }
  }
}

// combine per-row softmax stats over vocab tiles + target logit dot (merged)
__global__ __launch_bounds__(256) void vocab_combine_kernel(const float* __restrict__ tmax,
                                                            const float* __restrict__ tsum,
                                                            const ushort* __restrict__ headout,
                                                            const ushort* __restrict__ emb,
                                                            const int* __restrict__ tgt,
                                                            float* __restrict__ rmax,
                                                            float* __restrict__ rsum,
                                                            float* __restrict__ tl) {
  __shared__ float sred[4];
  int m = blockIdx.x;
  float mx = -3.4e38f;
  for (int t = threadIdx.x; t < NT_; t += 256) mx = fmaxf(mx, tmax[(size_t)m * NT_ + t]);
  mx = block_reduce_max(mx, sred);
  float s = 0.f;
  for (int t = threadIdx.x; t < NT_; t += 256)
    s += tsum[(size_t)m * NT_ + t] * expf(tmax[(size_t)m * NT_ + t] - mx);
  s = block_reduce_sum(s, sred);
  // target logit
  int si = m >> 3, b = m & 7;
  int t = tgt[b * S_ + si];
  const ushort* a = headout + (size_t)m * 2048;
  const ushort* w = emb + (size_t)t * D_;
  float acc = 0.f;
  for (int i = threadIdx.x; i < D_; i += 256) acc += bf2f(a[i]) * bf2f(w[i]);
  acc = block_reduce_sum(acc, sred);
  if (threadIdx.x == 0) { rmax[m] = mx; rsum[m] = s; tl[m] = acc; }
}

// ---------------- fused self-attention, one block per (b,h) ----------------
__global__ __launch_bounds__(256) void attn1_fused_kernel(const ushort* __restrict__ heads,
                                                          const ushort* __restrict__ rkproj,
                                                          const float* __restrict__ rw,
                                                          const float* __restrict__ rr,
                                                          ushort* __restrict__ attnA) {
  __shared__ float score[128][129];   // 66 KB
  __shared__ ushort pP[128][136];     // 34.8 KB
  __shared__ ushort vT[64][136];      // 17.4 KB
  int bz = blockIdx.x;
  int b = bz >> 4, n = bz & 15;
  int tid = threadIdx.x, lane = tid & 63, wave = tid >> 6;
  int quad = lane >> 4, l16 = lane & 15;
  int wrow = wave * 32;

  // stage V transposed: vT[d][j]
  {
    int j = tid >> 1, dbase = (tid & 1) * 32;
    const ushort* src = heads + (size_t)(j * 8 + b) * 3072 + 2048 + n * 64 + dbase;
#pragma unroll
    for (int c8 = 0; c8 < 4; ++c8) {
      short8 v8 = *(const short8*)(src + c8 * 8);
#pragma unroll
      for (int cc = 0; cc < 8; ++cc) vT[dbase + c8 * 8 + cc][j] = (ushort)v8[cc];
    }
  }

  // Q fragments with biases
  short8 qrw[2][2], qrr[2][2];
#pragma unroll
  for (int mi = 0; mi < 2; ++mi) {
    int i = wrow + mi * 16 + l16;
    const ushort* qp = heads + (size_t)(i * 8 + b) * 3072 + n * 64;
#pragma unroll
    for (int kc = 0; kc < 2; ++kc) {
      int k0 = kc * 32 + quad * 8;
      short8 qv = *(const short8*)(qp + k0);
      short8 w, rv;
#pragma unroll
      for (int t = 0; t < 8; ++t) {
        float q = bf2f((ushort)qv[t]);
        w[t] = (short)f2bf(q + rw[n * 64 + k0 + t]);
        rv[t] = (short)f2bf(q + rr[n * 64 + k0 + t]);
      }
      qrw[mi][kc] = w; qrr[mi][kc] = rv;
    }
  }

  // pass 1: AC -> score LDS
  {
    f32x4 acc[2][8];
#pragma unroll
    for (int i = 0; i < 2; ++i)
#pragma unroll
      for (int j = 0; j < 8; ++j) { acc[i][j][0]=0.f; acc[i][j][1]=0.f; acc[i][j][2]=0.f; acc[i][j][3]=0.f; }
#pragma unroll
    for (int kc = 0; kc < 2; ++kc) {
      int k0 = kc * 32 + quad * 8;
      short8 kf[8];
#pragma unroll
      for (int ni = 0; ni < 8; ++ni) {
        int j = ni * 16 + l16;
        kf[ni] = *(const short8*)(heads + (size_t)(j * 8 + b) * 3072 + 1024 + n * 64 + k0);
      }
#pragma unroll
      for (int mi = 0; mi < 2; ++mi)
#pragma unroll
        for (int ni = 0; ni < 8; ++ni)
          acc[mi][ni] = __builtin_amdgcn_mfma_f32_16x16x32_bf16(qrw[mi][kc], kf[ni], acc[mi][ni], 0, 0, 0);
    }
#pragma unroll
    for (int mi = 0; mi < 2; ++mi)
#pragma unroll
      for (int ni = 0; ni < 8; ++ni)
#pragma unroll
        for (int r = 0; r < 4; ++r)
          score[wrow + mi * 16 + quad * 4 + r][ni * 16 + l16] = acc[mi][ni][r];
  }
  // pass 2: BD pre-shift, add into score with rel-shift mapping
  {
    f32x4 acc[2][8];
#pragma unroll
    for (int i = 0; i < 2; ++i)
#pragma unroll
      for (int j = 0; j < 8; ++j) { acc[i][j][0]=0.f; acc[i][j][1]=0.f; acc[i][j][2]=0.f; acc[i][j][3]=0.f; }
#pragma unroll
    for (int kc = 0; kc < 2; ++kc) {
      int k0 = kc * 32 + quad * 8;
      short8 rkf[8];
#pragma unroll
      for (int ni = 0; ni < 8; ++ni) {
        int jp = ni * 16 + l16;
        rkf[ni] = *(const short8*)(rkproj + (size_t)jp * 1024 + n * 64 + k0);
      }
#pragma unroll
      for (int mi = 0; mi < 2; ++mi)
#pragma unroll
        for (int ni = 0; ni < 8; ++ni)
          acc[mi][ni] = __builtin_amdgcn_mfma_f32_16x16x32_bf16(qrr[mi][kc], rkf[ni], acc[mi][ni], 0, 0, 0);
    }
#pragma unroll
    for (int mi = 0; mi < 2; ++mi)
#pragma unroll
      for (int r = 0; r < 4; ++r) {
        int i = wrow + mi * 16 + quad * 4 + r;
#pragma unroll
        for (int ni = 0; ni < 8; ++ni) {
          int jp = ni * 16 + l16;
          if (jp >= 127 - i) score[i][jp - 127 + i] += acc[mi][ni][r];
        }
      }
  }
  // softmax (rows owned by same wave): row = tid>>1, half cols each
  {
    int row = tid >> 1, halfc = (tid & 1) * 64;
    float mx = -3.4e38f;
    for (int c = halfc; c < halfc + 64; ++c) {
      float v = (c <= row) ? score[row][c] * SCALE_F : -3.4e38f;
      mx = fmaxf(mx, v);
    }
    mx = fmaxf(mx, __shfl_xor(mx, 1));
    float s = 0.f;
    for (int c = halfc; c < halfc + 64; ++c) {
      float e = (c <= row) ? __expf(score[row][c] * SCALE_F - mx) : 0.f;
      score[row][c] = e;
      s += e;
    }
    s += __shfl_xor(s, 1);
    float inv = 1.0f / s;
    for (int c = halfc; c < halfc + 64; ++c) pP[row][c] = f2bf(score[row][c] * inv);
  }
  __syncthreads();  // vT + pP ready for all
  // PV: O[i][d] = sum_j P[i][j] V[j][d]
  {
    f32x4 acc[2][4];
#pragma unroll
    for (int i = 0; i < 2; ++i)
#pragma unroll
      for (int j = 0; j < 4; ++j) { acc[i][j][0]=0.f; acc[i][j][1]=0.f; acc[i][j][2]=0.f; acc[i][j][3]=0.f; }
#pragma unroll
    for (int kc = 0; kc < 4; ++kc) {
      int k0 = kc * 32 + quad * 8;
      short8 pf[2], vf[4];
#pragma unroll
      for (int mi = 0; mi < 2; ++mi)
        pf[mi] = *(const short8*)&pP[wrow + mi * 16 + l16][k0];
#pragma unroll
      for (int ni = 0; ni < 4; ++ni)
        vf[ni] = *(const short8*)&vT[ni * 16 + l16][k0];
#pragma unroll
      for (int mi = 0; mi < 2; ++mi)
#pragma unroll
        for (int ni = 0; ni < 4; ++ni)
          acc[mi][ni] = __builtin_amdgcn_mfma_f32_16x16x32_bf16(pf[mi], vf[ni], acc[mi][ni], 0, 0, 0);
    }
#pragma unroll
    for (int mi = 0; mi < 2; ++mi)
#pragma unroll
      for (int r = 0; r < 4; ++r) {
        int i = wrow + mi * 16 + quad * 4 + r;
#pragma unroll
        for (int ni = 0; ni < 4; ++ni)
          attnA[(size_t)(i * 8 + b) * 1024 + n * 64 + ni * 16 + l16] = f2bf(acc[mi][ni][r]);
      }
  }
}

// ---------------- fused cross-attention (flash over 4 E-tiles), block per (b,h) --------
__global__ __launch_bounds__(256) void attn2_fused_kernel(const float* __restrict__ q0,
                                                          const float* __restrict__ q1,
                                                          const ushort* __restrict__ kvproj,
                                                          const float* __restrict__ mask,
                                                          ushort* __restrict__ attnA) {
  __shared__ ushort vT[64][136];
  __shared__ ushort pP[128][136];
  __shared__ float mtile[128];
  int bz = blockIdx.x;
  int b = bz >> 4, n = bz & 15;
  int tid = threadIdx.x, lane = tid & 63, wave = tid >> 6;
  int quad = lane >> 4, l16 = lane & 15;
  int wrow = wave * 32;
  // Q frags: q0+q1 (split-K halves), f32 -> bf16
  short8 qf[2][2];
#pragma unroll
  for (int mi = 0; mi < 2; ++mi) {
    int i = wrow + mi * 16 + l16;
    size_t base = (size_t)(i * 8 + b) * 1024 + n * 64;
#pragma unroll
    for (int kc = 0; kc < 2; ++kc) {
      int k0 = kc * 32 + quad * 8;
      short8 v;
#pragma unroll
      for (int t = 0; t < 8; ++t) v[t] = (short)f2bf(q0[base + k0 + t] + q1[base + k0 + t]);
      qf[mi][kc] = v;
    }
  }
  float m_run[2][4], l_run[2][4];
#pragma unroll
  for (int mi = 0; mi < 2; ++mi)
#pragma unroll
    for (int r = 0; r < 4; ++r) { m_run[mi][r] = -3.0e38f; l_run[mi][r] = 0.f; }
  f32x4 accO[2][4];
#pragma unroll
  for (int i = 0; i < 2; ++i)
#pragma unroll
    for (int j = 0; j < 4; ++j) { accO[i][j][0]=0.f; accO[i][j][1]=0.f; accO[i][j][2]=0.f; accO[i][j][3]=0.f; }

  for (int et = 0; et < 4; ++et) {
    __syncthreads();  // previous tile's PV done before restaging
    // stage V2 tile transposed + mask tile
    {
      int j = tid >> 1, dbase = (tid & 1) * 32;
      int e = et * 128 + j;
      const ushort* src = kvproj + (size_t)(e * 8 + b) * 2048 + 1024 + n * 64 + dbase;
#pragma unroll
      for (int c8 = 0; c8 < 4; ++c8) {
        short8 v8 = *(const short8*)(src + c8 * 8);
#pragma unroll
        for (int cc = 0; cc < 8; ++cc) vT[dbase + c8 * 8 + cc][j] = (ushort)v8[cc];
      }
      if (tid < 128) mtile[tid] = (1.0f - mask[b * E_ + et * 128 + tid]) * NEGV;
    }
    // S tile
    f32x4 accS[2][8];
#pragma unroll
    for (int i = 0; i < 2; ++i)
#pragma unroll
      for (int j = 0; j < 8; ++j) { accS[i][j][0]=0.f; accS[i][j][1]=0.f; accS[i][j][2]=0.f; accS[i][j][3]=0.f; }
#pragma unroll
    for (int kc = 0; kc < 2; ++kc) {
      int k0 = kc * 32 + quad * 8;
      short8 kf[8];
#pragma unroll
      for (int ni = 0; ni < 8; ++ni) {
        int e = et * 128 + ni * 16 + l16;
        kf[ni] = *(const short8*)(kvproj + (size_t)(e * 8 + b) * 2048 + n * 64 + k0);
      }
#pragma unroll
      for (int mi = 0; mi < 2; ++mi)
#pragma unroll
        for (int ni = 0; ni < 8; ++ni)
          accS[mi][ni] = __builtin_amdgcn_mfma_f32_16x16x32_bf16(qf[mi][kc], kf[ni], accS[mi][ni], 0, 0, 0);
    }
    __syncthreads();  // vT, mtile ready
    // online softmax per owned row
#pragma unroll
    for (int mi = 0; mi < 2; ++mi)
#pragma unroll
      for (int r = 0; r < 4; ++r) {
        float v[8];
        float vmax = -3.4e38f;
#pragma unroll
        for (int ni = 0; ni < 8; ++ni) {
          v[ni] = accS[mi][ni][r] * SCALE_F + mtile[ni * 16 + l16];
          vmax = fmaxf(vmax, v[ni]);
        }
#pragma unroll
        for (int o = 1; o < 16; o <<= 1) vmax = fmaxf(vmax, __shfl_xor(vmax, o));
        float mnew = fmaxf(m_run[mi][r], vmax);
        float alpha = __expf(m_run[mi][r] - mnew);
        float ls = 0.f;
        int row = wrow + mi * 16 + quad * 4 + r;
#pragma unroll
        for (int ni = 0; ni < 8; ++ni) {
          float p = __expf(v[ni] - mnew);
          ls += p;
          pP[row][ni * 16 + l16] = f2bf(p);
        }
#pragma unroll
        for (int o = 1; o < 16; o <<= 1) ls += __shfl_xor(ls, o);
        l_run[mi][r] = l_run[mi][r] * alpha + ls;
        m_run[mi][r] = mnew;
#pragma unroll
        for (int ni = 0; ni < 4; ++ni) accO[mi][ni][r] *= alpha;
      }
    // PV accumulate (pP rows own-wave, vT via sync above)
#pragma unroll
    for (int kc = 0; kc < 4; ++kc) {
      int k0 = kc * 32 + quad * 8;
      short8 pf[2], vf[4];
#pragma unroll
      for (int mi = 0; mi < 2; ++mi)
        pf[mi] = *(const short8*)&pP[wrow + mi * 16 + l16][k0];
#pragma unroll
      for (int ni = 0; ni < 4; ++ni)
        vf[ni] = *(const short8*)&vT[ni * 16 + l16][k0];
#pragma unroll
      for (int mi = 0; mi < 2; ++mi)
#pragma unroll
        for (int ni = 0; ni < 4; ++ni)
          accO[mi][ni] = __builtin_amdgcn_mfma_f32_16x16x32_bf16(pf[mi], vf[ni], accO[mi][ni], 0, 0, 0);
    }
  }
  // finalize
#pragma unroll
  for (int mi = 0; mi < 2; ++mi)
#pragma unroll
    for (int r = 0; r < 4; ++r) {
      int i = wrow + mi * 16 + quad * 4 + r;
      float inv = 1.0f / l_run[mi][r];
#pragma unroll
      for (int ni = 0; ni < 4; ++ni)
        attnA[(size_t)(i * 8 + b) * 1024 + n * 64 + ni * 16 + l16] = f2bf(accO[mi][ni][r] * inv);
    }
}

// ---------------- add + layernorm with split-sum + optional bias + optional mode head --
__global__ __launch_bounds__(256) void addln_kernel(const float* __restrict__ a,
                                                    const float* __restrict__ c,
                                                    int nsplit, long long cstride,
                                                    const float* __restrict__ bias,
                                                    const float* __restrict__ g,
                                                    const float* __restrict__ bb,
                                                    float* __restrict__ out,
                                                    ushort* __restrict__ out_bf,
                                                    const float* __restrict__ mw,
                                                    const float* __restrict__ mb,
                                                    float* __restrict__ msig) {
  __shared__ float sred[4];
  int row = blockIdx.x;
  const float* pa = a + (size_t)row * D_;
  float vals[4];
  float s = 0.f;
#pragma unroll
  for (int it = 0; it < 4; ++it) {
    int idx = threadIdx.x + it * 256;
    float v = pa[idx];
    for (int sp = 0; sp < nsplit; ++sp) v += c[(size_t)sp * cstride + (size_t)row * D_ + idx];
    if (bias) v += bias[idx];
    vals[it] = v;
    s += v;
  }
  s = block_reduce_sum(s, sred);
  float mean = s * (1.0f / D_);
  float ss = 0.f;
#pragma unroll
  for (int it = 0; it < 4; ++it) {
    float dd = vals[it] - mean;
    ss += dd * dd;
  }
  ss = block_reduce_sum(ss, sred);
  float inv = rsqrtf(ss * (1.0f / D_) + 1e-5f);
#pragma unroll
  for (int it = 0; it < 4; ++it) {
    int idx = threadIdx.x + it * 256;
    float r = (vals[it] - mean) * inv * g[idx] + bb[idx];
    vals[it] = r;
    out[(size_t)row * D_ + idx] = r;
    out_bf[(size_t)row * D_ + idx] = f2bf(r);
  }
  if (mw) {  // fused mode head (last layer only): sigmoid(core . mode_w + mode_b)
    float sm = 0.f;
#pragma unroll
    for (int it = 0; it < 4; ++it) {
      int idx = threadIdx.x + it * 256;
      sm += vals[it] * mw[idx];
    }
    sm = block_reduce_sum(sm, sred);
    if (threadIdx.x == 0) msig[row] = 1.0f / (1.0f + expf(-(sm + mb[0])));
  }
}

// ---------------- final: copy attention + loss ----------------
__global__ __launch_bounds__(256) void final_kernel(const float* __restrict__ lg,
                                                    const int* __restrict__ ids,
                                                    const float* __restrict__ mask,
                                                    const int* __restrict__ tgt,
                                                    const float* __restrict__ mode_sig,
                                                    const float* __restrict__ tlogit,
                                                    const float* __restrict__ rmax,
                                                    const float* __restrict__ rsum,
                                                    float* __restrict__ loss_acc) {
  __shared__ float sred[4];
  int s = blockIdx.x, b = blockIdx.y;
  int m = s * B_ + b;
  size_t base = (size_t)(b * S_ + s) * E_;
  const long long LGS = (long long)B_ * S_ * E_;
  int tg = tgt[b * S_ + s];
  float lv[2];
  float mx = -3.4e38f;
#pragma unroll
  for (int it = 0; it < 2; ++it) {
    int e = threadIdx.x + it * 256;
    float raw = 0.f;
#pragma unroll
    for (int sp = 0; sp < 4; ++sp) raw += lg[sp * LGS + base + e];
    raw += (1.0f - mask[b * E_ + e]) * NEGV;
    lv[it] = raw;
    mx = fmaxf(mx, raw);
  }
  mx = block_reduce_max(mx, sred);
  float ssum = 0.f, csum = 0.f;
#pragma unroll
  for (int it = 0; it < 2; ++it) {
    int e = threadIdx.x + it * 256;
    float ev = expf(lv[it] - mx);
    ssum += ev;
    if (ids[b * E_ + e] == tg) csum += ev;
  }
  ssum = block_reduce_sum(ssum, sred);
  csum = block_reduce_sum(csum, sred);
  if (threadIdx.x == 0) {
    float copy_p = csum / ssum;
    float pv = expf(tlogit[m] - rmax[m]) / rsum[m];
    float msig = mode_sig[m];
    float predict = pv * msig + (1.0f - msig) * copy_p;
    float valid = (tg != 0) ? 1.0f : 0.0f;
    atomicAdd(&loss_acc[0], -logf(predict + 1e-6f) * valid);
    atomicAdd(&loss_acc[1], valid);
  }
}

__global__ void writeout_kernel(const float* __restrict__ loss_acc, float* __restrict__ out) {
  if (threadIdx.x < B_) out[threadIdx.x] = loss_acc[0] / loss_acc[1];
}

// ---------------- host ----------------
static void gw(hipStream_t st, int epi, const ushort* A, const ushort* B, const float* bias,
               void* C, int M, int N, int K,
               long long Ar, long long Ab, long long Br, long long Bb,
               long long Cr, long long Cb, int nb, int ksplit, long long Csplit) {
  dim3 g(N / 128, M / 128, nb * ksplit);
  switch (epi) {
    case 0: gemm_w_kernel<0><<<g, 256, 0, st>>>(A, B, bias, C, M, N, K, ksplit, Ar, Ab, Br, Bb, Cr, Cb, Csplit); break;
    case 1: gemm_w_kernel<1><<<g, 256, 0, st>>>(A, B, bias, C, M, N, K, ksplit, Ar, Ab, Br, Bb, Cr, Cb, Csplit); break;
    case 3: gemm_w_kernel<3><<<g, 256, 0, st>>>(A, B, bias, C, M, N, K, ksplit, Ar, Ab, Br, Bb, Cr, Cb, Csplit); break;
    case 4: gemm_w_kernel<4><<<g, 256, 0, st>>>(A, B, bias, C, M, N, K, ksplit, Ar, Ab, Br, Bb, Cr, Cb, Csplit); break;
  }
}
static void castTo(hipStream_t st, const float* src, ushort* dst, size_t count) {
  int n4 = (int)(count / 4);
  castf_kernel<<<(n4 + 255) / 256, 256, 0, st>>>(src, dst, n4);
}

extern "C" void kernel_launch(void* const* d_in, const int* in_sizes, int n_in,
                              void* d_out, int out_size, void* d_ws, size_t ws_size,
                              hipStream_t stream) {
  const int* input_ids = (const int*)d_in[0];
  const float* encoder_rep = (const float*)d_in[1];
  const float* input_mask = (const float*)d_in[2];
  const int* decode_input = (const int*)d_in[3];
  const int* decode_target = (const int*)d_in[4];
  const float* word_emb = (const float*)d_in[5];
  const float* qkv_w = (const float*)d_in[6];
  const float* r_w = (const float*)d_in[7];
  const float* o_w = (const float*)d_in[8];
  const float* kv_w = (const float*)d_in[9];
  const float* q_w = (const float*)d_in[10];
  const float* io_w = (const float*)d_in[11];
  const float* rr_bias = (const float*)d_in[12];
  const float* rw_bias = (const float*)d_in[13];
  const float* ln1_g = (const float*)d_in[14];
  const float* ln1_b = (const float*)d_in[15];
  const float* ln2_g = (const float*)d_in[16];
  const float* ln2_b = (const float*)d_in[17];
  const float* ffn_w1 = (const float*)d_in[18];
  const float* ffn_b1 = (const float*)d_in[19];
  const float* ffn_w2 = (const float*)d_in[20];
  const float* ffn_b2 = (const float*)d_in[21];
  const float* ln3_g = (const float*)d_in[22];
  const float* ln3_b = (const float*)d_in[23];
  const float* out_w = (const float*)d_in[24];
  const float* out_b = (const float*)d_in[25];
  const float* copy_w = (const float*)d_in[26];
  const float* copy_b = (const float*)d_in[27];
  const float* mode_w = (const float*)d_in[28];
  const float* mode_b = (const float*)d_in[29];
  float* out = (float*)d_out;

  char* base = (char*)d_ws;
  size_t off = 0;
  auto alloc = [&](size_t bytes) -> void* {
    void* p = base + off;
    off = (off + bytes + 255) & ~(size_t)255;
    return p;
  };

  // per-layer weight buffers (cast each layer, merged into one dispatch)
  ushort* wl_qkv = (ushort*)alloc((size_t)3 * D_ * D_ * 2);
  ushort* wl_o = (ushort*)alloc((size_t)D_ * D_ * 2);
  ushort* wl_q = (ushort*)alloc((size_t)D_ * D_ * 2);
  ushort* wl_io = (ushort*)alloc((size_t)D_ * D_ * 2);
  ushort* wl_f1 = (ushort*)alloc((size_t)FF_ * D_ * 2);
  ushort* wl_f2 = (ushort*)alloc((size_t)FF_ * D_ * 2);
  // hoisted all-layer buffers (encoder-side work batched upfront)
  ushort* wl_kv = (ushort*)alloc((size_t)L_ * 2 * D_ * D_ * 2);
  ushort* wl_r = (ushort*)alloc((size_t)L_ * D_ * D_ * 2);
  ushort* kvproj_bf = (ushort*)alloc((size_t)L_ * ME_ * 2 * D_ * 2);
  ushort* rkproj_bf = (ushort*)alloc((size_t)L_ * S_ * D_ * 2);

  ushort* w_emb = (ushort*)alloc((size_t)V_ * D_ * 2);
  ushort* w_oc = (ushort*)alloc((size_t)2048 * D_ * 2);
  float* b_oc = (float*)alloc(2048 * 4);
  ushort* enc_bf = (ushort*)alloc((size_t)ME_ * D_ * 2);
  ushort* encT_bf = (ushort*)alloc((size_t)ME_ * D_ * 2);
  ushort* r_bf = (ushort*)alloc((size_t)S_ * D_ * 2);
  float* f_core = (float*)alloc((size_t)M_ * D_ * 4);
  ushort* core_bf = (ushort*)alloc((size_t)M_ * D_ * 2);
  ushort* heads_bf = (ushort*)alloc((size_t)M_ * 3 * D_ * 2);
  ushort* attnA_bf = (ushort*)alloc((size_t)M_ * D_ * 2);
  float* f_tmp = (float*)alloc((size_t)4 * M_ * D_ * 4);   // up to 4 split buffers
  float* f_x = (float*)alloc((size_t)M_ * D_ * 4);
  ushort* x_bf = (ushort*)alloc((size_t)M_ * D_ * 2);
  float* f_y = (float*)alloc((size_t)M_ * D_ * 4);
  ushort* y_bf = (ushort*)alloc((size_t)M_ * D_ * 2);
  float* f_q = (float*)alloc((size_t)2 * M_ * D_ * 4);      // q split buffers
  ushort* ffnh_bf = (ushort*)alloc((size_t)M_ * FF_ * 2);
  ushort* headout_bf = (ushort*)alloc((size_t)M_ * 2048 * 2);
  float* f_lg = (float*)alloc((size_t)4 * B_ * S_ * E_ * 4);
  float* f_tmax = (float*)alloc((size_t)M_ * NT_ * 4);
  float* f_tsum = (float*)alloc((size_t)M_ * NT_ * 4);
  float* f_rmax = (float*)alloc(M_ * 4);
  float* f_rsum = (float*)alloc(M_ * 4);
  float* f_tlogit = (float*)alloc(M_ * 4);
  float* f_mode = (float*)alloc(M_ * 4);
  float* f_loss = (float*)alloc(64);

  // global casts + setup
  castTo(stream, word_emb, w_emb, (size_t)V_ * D_);
  castTo(stream, out_w, w_oc, (size_t)D_ * D_);
  castTo(stream, copy_w, w_oc + (size_t)D_ * D_, (size_t)D_ * D_);
  hipMemcpyAsync(b_oc, out_b, D_ * 4, hipMemcpyDeviceToDevice, stream);
  hipMemcpyAsync(b_oc + D_, copy_b, D_ * 4, hipMemcpyDeviceToDevice, stream);
  enc_both_kernel<<<(ME_ * D_) / 256, 256, 0, stream>>>(encoder_rep, enc_bf, encT_bf);
  pos_emb_kernel<<<(S_ * D_ + 255) / 256, 256, 0, stream>>>(r_bf);
  embed_kernel<<<(M_ * D_) / 256, 256, 0, stream>>>(decode_input, word_emb, f_core, core_bf);

  // hoisted: all-layer kv/r weight casts + batched encoder-side projections
  castTo(stream, kv_w, wl_kv, (size_t)L_ * 2 * D_ * D_);
  castTo(stream, r_w, wl_r, (size_t)L_ * D_ * D_);
  // kvproj[l] = encT @ kv_w[l]^T : 256^2 deep-pipelined, batched over layers
  gemm256_kernel<1><<<dim3(2 * D_ / 256, ME_ / 256, L_), 512, 0, stream>>>(
      encT_bf, wl_kv, kvproj_bf, nullptr, nullptr,
      D_, 0, D_, (long long)2 * D_ * D_, 2 * D_, (long long)ME_ * 2 * D_);
  // rkproj[l] = r @ r_w[l]^T : batched over layers (32 blocks, small)
  gw(stream, 1, r_bf, wl_r, nullptr, rkproj_bf, S_, D_, D_,
     D_, 0, D_, (long long)D_ * D_, D_, (long long)S_ * D_, L_, 1, 0);

  for (int l = 0; l < L_; ++l) {
    // one merged cast for this layer's decoder-side weights
    castlayer_kernel<<<14336, 256, 0, stream>>>(
        qkv_w + (size_t)l * 3 * D_ * D_, o_w + (size_t)l * D_ * D_,
        q_w + (size_t)l * D_ * D_, io_w + (size_t)l * D_ * D_,
        ffn_w1 + (size_t)l * FF_ * D_, ffn_w2 + (size_t)l * FF_ * D_,
        wl_qkv, wl_o, wl_q, wl_io, wl_f1, wl_f2);

    // self-attention
    gw(stream, 1, core_bf, wl_qkv, nullptr, heads_bf, M_, 3 * D_, D_, D_, 0, D_, 0, 3 * D_, 0, 1, 1, 0);
    attn1_fused_kernel<<<B_ * H_, 256, 0, stream>>>(heads_bf, rkproj_bf + (size_t)l * S_ * D_,
                                                    rw_bias + (size_t)l * D_,
                                                    rr_bias + (size_t)l * D_, attnA_bf);
    gw(stream, 0, attnA_bf, wl_o, nullptr, f_tmp, M_, D_, D_, D_, 0, D_, 0, D_, 0, 1, 2,
       (long long)M_ * D_);
    addln_kernel<<<M_, 256, 0, stream>>>(f_core, f_tmp, 2, (long long)M_ * D_, nullptr,
                                         ln1_g + (size_t)l * D_, ln1_b + (size_t)l * D_, f_x, x_bf,
                                         nullptr, nullptr, nullptr);

    // cross-attention (kvproj precomputed upfront)
    gw(stream, 0, x_bf, wl_q, nullptr, f_q, M_, D_, D_, D_, 0, D_, 0, D_, 0, 1, 2,
       (long long)M_ * D_);
    attn2_fused_kernel<<<B_ * H_, 256, 0, stream>>>(f_q, f_q + (size_t)M_ * D_,
                                                    kvproj_bf + (size_t)l * ME_ * 2 * D_,
                                                    input_mask, attnA_bf);
    gw(stream, 0, attnA_bf, wl_io, nullptr, f_tmp, M_, D_, D_, D_, 0, D_, 0, D_, 0, 1, 2,
       (long long)M_ * D_);
    addln_kernel<<<M_, 256, 0, stream>>>(f_x, f_tmp, 2, (long long)M_ * D_, nullptr,
                                         ln2_g + (size_t)l * D_, ln2_b + (size_t)l * D_, f_y, y_bf,
                                         nullptr, nullptr, nullptr);

    // FFN
    gw(stream, 4, y_bf, wl_f1, ffn_b1 + (size_t)l * FF_, ffnh_bf, M_, FF_, D_, D_, 0, D_, 0, FF_, 0, 1, 1, 0);
    gw(stream, 0, ffnh_bf, wl_f2, nullptr, f_tmp, M_, D_, FF_, FF_, 0, FF_, 0, D_, 0, 1, 4,
       (long long)M_ * D_);
    // last layer: fuse mode head into the addln (saves mode_kernel dispatch)
    bool last = (l == L_ - 1);
    addln_kernel<<<M_, 256, 0, stream>>>(f_y, f_tmp, 4, (long long)M_ * D_,
                                         ffn_b2 + (size_t)l * D_,
                                         ln3_g + (size_t)l * D_, ln3_b + (size_t)l * D_, f_core, core_bf,
                                         last ? mode_w : nullptr, last ? mode_b : nullptr,
                                         last ? f_mode : nullptr);
  }

  // merged output+copy head GEMM: [M,2048]
  gw(stream, 3, core_bf, w_oc, b_oc, headout_bf, M_, 2048, D_, D_, 0, D_, 0, 2048, 0, 1, 1, 0);

  // vocab softmax stats: 256^2 deep-pipelined + fused stats epilogue (500 blocks)
  gemm256_kernel<5><<<500, 512, 0, stream>>>(headout_bf, w_emb, nullptr, f_tmax, f_tsum,
                                             2048, 0, D_, 0, 0, 0);
  vocab_combine_kernel<<<M_, 256, 0, stream>>>(f_tmax, f_tsum, headout_bf, w_emb, decode_target,
                                               f_rmax, f_rsum, f_tlogit);

  // copy logits: batched over b, split-K 4
  gw(stream, 0, headout_bf + D_, enc_bf, nullptr, f_lg, S_, E_, D_,
     (long long)B_ * 2048, 2048, D_, (long long)E_ * D_, E_, (long long)S_ * E_, B_, 4,
     (long long)B_ * S_ * E_);

  hipMemsetAsync(f_loss, 0, 2 * sizeof(float), stream);
  final_kernel<<<dim3(S_, B_), 256, 0, stream>>>(f_lg, input_ids, input_mask, decode_target,
                                                 f_mode, f_tlogit, f_rmax, f_rsum, f_loss);
  writeout_kernel<<<1, 64, 0, stream>>>(f_loss, out);
}